// Round 1
// baseline (1490.061 us; speedup 1.0000x reference)
//
#include <hip/hip_runtime.h>
#include <math.h>

#define CH 128
#define IMGH 256
#define IMGW 256
#define NIMG 10
#define HW (IMGH*IMGW)                      // 65536
#define FEATS_ELEMS ((size_t)NIMG*CH*HW)    // 83886080
#define GN_EPS 1e-5f
#define NWIN 10240                          // 10 * 32 * 32 windows
#define INV_LOSS_COUNT (1.0f/655360.0f)     // 1/(Nw*64)

// workspace layout (float offsets)
#define WS_W1T  0                           // [128][128] W1 transposed: W1T[k][o]
#define WS_W2T  16384
#define WS_SUM  32768                       // [10][8] group sums of h
#define WS_SQ   32848                       // [10][8] group sums of h^2
#define WS_A    32928                       // [10][128] rsig*gn_w
#define WS_CC   34208                       // [10][128] gn_b - mu*rsig*gn_w
#define WS_LOSS 35488                       // [10240] per-window loss partials

// ---------------------------------------------------------------- K0: init
__global__ void k0_init(const float* __restrict__ W1, const float* __restrict__ W2,
                        float* __restrict__ ws) {
    int idx = blockIdx.x * 256 + threadIdx.x;   // 0..32767
    if (idx < 16384) {
        int o = idx >> 7, k = idx & 127;
        ws[WS_W1T + k*CH + o] = W1[idx];
    } else {
        int j = idx - 16384;
        int o = j >> 7, k = j & 127;
        ws[WS_W2T + k*CH + o] = W2[j];
    }
    if (blockIdx.x == 0 && threadIdx.x < 160) ws[WS_SUM + threadIdx.x] = 0.0f;
}

// ------------------------------------------------- K1: group-norm statistics
// One block = one n + 64 consecutive spatial positions. Recompute h = W1*x+b1
// tile-wise, accumulate sum/sumsq per group via atomics.
__global__ __launch_bounds__(256) void k1_stats(const float* __restrict__ x,
                                                float* ws,
                                                const float* __restrict__ b1) {
    __shared__ __align__(16) float xs[CH*64];           // xs[k][p]
    const int t = threadIdx.x, b = blockIdx.x;
    const int n = b >> 10, tile = b & 1023;
    const float* xbase = x + (size_t)n*CH*HW + (size_t)tile*64;
    #pragma unroll
    for (int i = 0; i < 8; ++i) {
        int f4 = t + i*256;                  // float4 index 0..2047
        int k = f4 >> 4, pq = f4 & 15;
        float4 v = *(const float4*)(xbase + (size_t)k*HW + pq*4);
        *(float4*)&xs[k*64 + pq*4] = v;
    }
    __syncthreads();

    const int pt = t & 15, ot = t >> 4;
    const int p0 = pt*4, o0 = ot*8;
    float acc[8][4];
    #pragma unroll
    for (int j = 0; j < 8; ++j) {
        float bv = b1[o0 + j];
        acc[j][0]=bv; acc[j][1]=bv; acc[j][2]=bv; acc[j][3]=bv;
    }
    const float* wT = ws + WS_W1T + o0;
    #pragma unroll 4
    for (int k = 0; k < CH; ++k) {
        float4 xv = *(const float4*)&xs[k*64 + p0];
        float4 wa = *(const float4*)(wT + k*CH);
        float4 wb = *(const float4*)(wT + k*CH + 4);
        float wv[8]  = {wa.x,wa.y,wa.z,wa.w, wb.x,wb.y,wb.z,wb.w};
        float xvv[4] = {xv.x,xv.y,xv.z,xv.w};
        #pragma unroll
        for (int j = 0; j < 8; ++j)
            #pragma unroll
            for (int i = 0; i < 4; ++i)
                acc[j][i] = fmaf(wv[j], xvv[i], acc[j][i]);
    }
    float s1 = 0.0f, s2 = 0.0f;
    #pragma unroll
    for (int j = 0; j < 8; ++j)
        #pragma unroll
        for (int i = 0; i < 4; ++i) { float h = acc[j][i]; s1 += h; s2 += h*h; }
    // threads t..t+31 share one group (g = t>>5); reduce 32-lane halves
    #pragma unroll
    for (int off = 16; off > 0; off >>= 1) {
        s1 += __shfl_down(s1, off, 32);
        s2 += __shfl_down(s2, off, 32);
    }
    if ((t & 31) == 0) {
        int g = t >> 5;
        atomicAdd(&ws[WS_SUM + n*8 + g], s1);
        atomicAdd(&ws[WS_SQ  + n*8 + g], s2);
    }
}

// ----------------------------------------------- K2: finalize affine factors
__global__ void k2_final(const float* __restrict__ gnw, const float* __restrict__ gnb,
                         float* ws) {
    __shared__ float muS[80], rsS[80];
    int t = threadIdx.x;
    if (t < 80) {
        const float cnt = 1048576.0f;        // 16 * 65536
        float mu  = ws[WS_SUM + t] / cnt;
        float var = ws[WS_SQ  + t] / cnt - mu*mu;
        muS[t] = mu;
        rsS[t] = rsqrtf(var + GN_EPS);
    }
    __syncthreads();
    for (int idx = t; idx < 1280; idx += 256) {
        int n = idx >> 7, o = idx & 127;
        int gi = n*8 + (o >> 4);
        float a = rsS[gi] * gnw[o];
        ws[WS_A  + idx] = a;
        ws[WS_CC + idx] = gnb[o] - muS[gi] * a;
    }
}

// -------------------------------------- K3: fused projector + windowed loss
// One block per 8x8 window: conv1 -> GN -> GELU -> conv2 -> store feats ->
// 64x64 Gram -> row LSE -> loss partial.
__global__ __launch_bounds__(256) void k3_fused(const float* __restrict__ x,
                                                float* ws,
                                                const float* __restrict__ b1,
                                                const float* __restrict__ b2,
                                                const float* __restrict__ temp,
                                                float* __restrict__ out) {
    __shared__ __align__(16) float bufA[CH*64];   // xs -> fsC -> red arrays
    __shared__ __align__(16) float bufB[CH*64];   // gs -> sim[64][68]
    const int t = threadIdx.x, b = blockIdx.x;
    const int n = b >> 10, widx = b & 1023;
    const int h0 = (widx >> 5) * 8, w0 = (widx & 31) * 8;

    // ---- stage x window: xs[k][p], p = dy*8+dx
    const float* xbase = x + (size_t)n*CH*HW + (size_t)h0*IMGW + w0;
    #pragma unroll
    for (int i = 0; i < 8; ++i) {
        int f4 = t + i*256;                   // 0..2047
        int row = f4 >> 1, half = f4 & 1;     // row = k*8+dy
        int k = row >> 3, dy = row & 7;
        float4 v = *(const float4*)(xbase + (size_t)k*HW + dy*IMGW + half*4);
        *(float4*)&bufA[k*64 + dy*8 + half*4] = v;
    }
    __syncthreads();

    const int pt = t & 15, ot = t >> 4;
    const int p0 = pt*4, o0 = ot*8;

    // ---- phase 2: h = W1*x + b1 (thread tile 8o x 4p)
    float acc[8][4];
    #pragma unroll
    for (int j = 0; j < 8; ++j) {
        float bv = b1[o0 + j];
        acc[j][0]=bv; acc[j][1]=bv; acc[j][2]=bv; acc[j][3]=bv;
    }
    {
        const float* wT = ws + WS_W1T + o0;
        #pragma unroll 4
        for (int k = 0; k < CH; ++k) {
            float4 xv = *(const float4*)&bufA[k*64 + p0];
            float4 wa = *(const float4*)(wT + k*CH);
            float4 wb = *(const float4*)(wT + k*CH + 4);
            float wv[8]  = {wa.x,wa.y,wa.z,wa.w, wb.x,wb.y,wb.z,wb.w};
            float xvv[4] = {xv.x,xv.y,xv.z,xv.w};
            #pragma unroll
            for (int j = 0; j < 8; ++j)
                #pragma unroll
                for (int i = 0; i < 4; ++i)
                    acc[j][i] = fmaf(wv[j], xvv[i], acc[j][i]);
        }
    }
    // ---- GroupNorm affine + exact GELU, write gs[k][p] into bufB
    {
        const float* aP = ws + WS_A  + n*CH + o0;
        const float* cP = ws + WS_CC + n*CH + o0;
        #pragma unroll
        for (int j = 0; j < 8; ++j) {
            float a = aP[j], cc = cP[j];
            float4 gv;
            float hn0 = fmaf(acc[j][0], a, cc);
            float hn1 = fmaf(acc[j][1], a, cc);
            float hn2 = fmaf(acc[j][2], a, cc);
            float hn3 = fmaf(acc[j][3], a, cc);
            gv.x = 0.5f*hn0*(1.0f + erff(hn0*0.70710678118654752f));
            gv.y = 0.5f*hn1*(1.0f + erff(hn1*0.70710678118654752f));
            gv.z = 0.5f*hn2*(1.0f + erff(hn2*0.70710678118654752f));
            gv.w = 0.5f*hn3*(1.0f + erff(hn3*0.70710678118654752f));
            *(float4*)&bufB[(o0+j)*64 + p0] = gv;
        }
    }
    __syncthreads();

    // ---- phase 3: feats = W2*g + b2
    float f[8][4];
    #pragma unroll
    for (int j = 0; j < 8; ++j) {
        float bv = b2[o0 + j];
        f[j][0]=bv; f[j][1]=bv; f[j][2]=bv; f[j][3]=bv;
    }
    {
        const float* wT = ws + WS_W2T + o0;
        #pragma unroll 4
        for (int k = 0; k < CH; ++k) {
            float4 xv = *(const float4*)&bufB[k*64 + p0];
            float4 wa = *(const float4*)(wT + k*CH);
            float4 wb = *(const float4*)(wT + k*CH + 4);
            float wv[8]  = {wa.x,wa.y,wa.z,wa.w, wb.x,wb.y,wb.z,wb.w};
            float xvv[4] = {xv.x,xv.y,xv.z,xv.w};
            #pragma unroll
            for (int j = 0; j < 8; ++j)
                #pragma unroll
                for (int i = 0; i < 4; ++i)
                    f[j][i] = fmaf(wv[j], xvv[i], f[j][i]);
        }
    }
    // ---- write feats to global (float4) and fsC[c][p] into bufA
    {
        const int dy0 = p0 >> 3, dx0 = p0 & 7;
        float* obase = out + (size_t)n*CH*HW + (size_t)(h0+dy0)*IMGW + w0 + dx0;
        #pragma unroll
        for (int j = 0; j < 8; ++j) {
            float4 fv = make_float4(f[j][0], f[j][1], f[j][2], f[j][3]);
            *(float4*)(obase + (size_t)(o0+j)*HW) = fv;
            *(float4*)&bufA[(o0+j)*64 + p0] = fv;
        }
    }
    __syncthreads();

    // ---- phase 4: Gram sim[p][q] = f_p . f_q / T  (thread tile 4p x 4q)
    const float invT = 1.0f / temp[0];
    {
        const int pg = (t & 15) * 4, qg = (t >> 4) * 4;
        float sacc[4][4];
        #pragma unroll
        for (int i = 0; i < 4; ++i)
            #pragma unroll
            for (int j = 0; j < 4; ++j) sacc[i][j] = 0.0f;
        #pragma unroll 4
        for (int c = 0; c < CH; ++c) {
            float4 fp = *(const float4*)&bufA[c*64 + pg];
            float4 fq = *(const float4*)&bufA[c*64 + qg];
            float fpv[4] = {fp.x,fp.y,fp.z,fp.w};
            float fqv[4] = {fq.x,fq.y,fq.z,fq.w};
            #pragma unroll
            for (int i = 0; i < 4; ++i)
                #pragma unroll
                for (int j = 0; j < 4; ++j)
                    sacc[i][j] = fmaf(fpv[i], fqv[j], sacc[i][j]);
        }
        #pragma unroll
        for (int i = 0; i < 4; ++i) {
            float4 sv = make_float4(sacc[i][0]*invT, sacc[i][1]*invT,
                                    sacc[i][2]*invT, sacc[i][3]*invT);
            *(float4*)&bufB[(pg+i)*68 + qg] = sv;   // sim[64][68] (padded)
        }
    }
    __syncthreads();

    // ---- phase 5: per-row logsumexp, loss partial
    {
        const int p = t & 63, qs = (t >> 6) * 16;
        float sv[16]; float m = -1e30f;
        #pragma unroll
        for (int j = 0; j < 16; ++j) { sv[j] = bufB[p*68 + qs + j]; m = fmaxf(m, sv[j]); }
        bufA[t] = m;                               // redM[4][64]
        __syncthreads();
        float mAll = fmaxf(fmaxf(bufA[p], bufA[64+p]), fmaxf(bufA[128+p], bufA[192+p]));
        float s = 0.0f;
        #pragma unroll
        for (int j = 0; j < 16; ++j) s += expf(sv[j] - mAll);
        bufA[256 + t] = s;                         // redS[4][64]
        __syncthreads();
        if (t < 64) {
            float sAll = bufA[256+p] + bufA[320+p] + bufA[384+p] + bufA[448+p];
            float lse  = mAll + logf(sAll);
            float loss = lse - bufB[p*68 + p];     // lse - sim[p][p]
            #pragma unroll
            for (int off = 32; off > 0; off >>= 1) loss += __shfl_down(loss, off, 64);
            if (t == 0) ws[WS_LOSS + b] = loss;
        }
    }
}

// ------------------------------------------ K4: deterministic loss reduction
__global__ void k4_loss(const float* __restrict__ ws, float* __restrict__ out) {
    __shared__ float red[4];
    int t = threadIdx.x;
    float s = 0.0f;
    for (int i = t; i < NWIN; i += 256) s += ws[WS_LOSS + i];
    #pragma unroll
    for (int off = 32; off > 0; off >>= 1) s += __shfl_down(s, off, 64);
    if ((t & 63) == 0) red[t >> 6] = s;
    __syncthreads();
    if (t == 0) out[FEATS_ELEMS] = (red[0] + red[1] + red[2] + red[3]) * INV_LOSS_COUNT;
}

// ---------------------------------------------------------------- launcher
extern "C" void kernel_launch(void* const* d_in, const int* in_sizes, int n_in,
                              void* d_out, int out_size, void* d_ws, size_t ws_size,
                              hipStream_t stream) {
    (void)in_sizes; (void)n_in; (void)out_size; (void)ws_size;
    const float* x    = (const float*)d_in[0];
    const float* W1   = (const float*)d_in[1];
    const float* b1   = (const float*)d_in[2];
    const float* gnw  = (const float*)d_in[3];
    const float* gnb  = (const float*)d_in[4];
    const float* W2   = (const float*)d_in[5];
    const float* b2   = (const float*)d_in[6];
    const float* temp = (const float*)d_in[7];
    float* out = (float*)d_out;
    float* ws  = (float*)d_ws;

    hipLaunchKernelGGL(k0_init,  dim3(128),   dim3(256), 0, stream, W1, W2, ws);
    hipLaunchKernelGGL(k1_stats, dim3(NWIN),  dim3(256), 0, stream, x, ws, b1);
    hipLaunchKernelGGL(k2_final, dim3(1),     dim3(256), 0, stream, gnw, gnb, ws);
    hipLaunchKernelGGL(k3_fused, dim3(NWIN),  dim3(256), 0, stream, x, ws, b1, b2, temp, out);
    hipLaunchKernelGGL(k4_loss,  dim3(1),     dim3(256), 0, stream, ws, out);
}

// Round 2
// 607.446 us; speedup vs baseline: 2.4530x; 2.4530x over previous
//
#include <hip/hip_runtime.h>
#include <hip/hip_bf16.h>
#include <math.h>

#define CH 128
#define IMGW 256
#define NIMG 10
#define HW 65536
#define FEATS_ELEMS ((size_t)NIMG*CH*HW)
#define NWIN 10240

typedef __attribute__((ext_vector_type(8))) short short8;
typedef __attribute__((ext_vector_type(4))) float f32x4;

// workspace layout (float offsets)
#define WS_W1BF 0          // W1 bf16 [128][128] row-major (o,k) = 8192 floats
#define WS_W2BF 8192
#define WS_M    16384      // [10][128][128] fp32 second moments
#define WS_CS   180224     // [10][128] column sums of x
#define WS_A    181504     // [10][128] rsig*gn_w
#define WS_CC   182784     // [10][128] gnb + (b1-mu)*a
#define WS_LOSS 184064     // [40960] per-(window,wave) loss partials

static __device__ __forceinline__ ushort f2bf(float f) {
    __hip_bfloat16 h = __float2bfloat16(f);
    return *reinterpret_cast<ushort*>(&h);
}
static __device__ __forceinline__ uint pack2(float a, float b) {
    return (uint)f2bf(a) | ((uint)f2bf(b) << 16);
}

// ------------------------------------------------ K0: W->bf16, zero M/colsum
__global__ void k0_init(const float* __restrict__ W1, const float* __restrict__ W2,
                        float* __restrict__ ws) {
    int idx = blockIdx.x*256 + threadIdx.x;
    uint* w1b = (uint*)(ws + WS_W1BF);
    uint* w2b = (uint*)(ws + WS_W2BF);
    if (idx < 8192) {
        w1b[idx] = pack2(W1[2*idx], W1[2*idx+1]);
    } else if (idx < 16384) {
        int j = idx - 8192;
        w2b[j] = pack2(W2[2*j], W2[2*j+1]);
    } else if (idx < 16384 + 165120) {
        ws[WS_M + (idx - 16384)] = 0.0f;   // M + colsum regions
    }
}

// ------------------------------- K1: bf16 MFMA syrk M = X*X^T + column sums
// grid 640: (n, 64 chunks of 1024 spatial). LDS tile [128c][64s] bf16,
// XOR-swizzled s-index for conflict-spread ds_read_b128 fragments.
__global__ __launch_bounds__(256) void k1_syrk(const float* __restrict__ x,
                                               float* ws) {
    __shared__ __align__(16) ushort xbS[128*64];
    const int t = threadIdx.x, b = blockIdx.x;
    const int n = b >> 6, chunk = b & 63;
    const int l = t & 63, wid = t >> 6;
    const int lm = l & 15, lg = l >> 4;
    const float* xbase = x + (size_t)n*CH*HW + chunk*1024;

    f32x4 acc[2][8];
    #pragma unroll
    for (int rt = 0; rt < 2; ++rt)
        #pragma unroll
        for (int ct = 0; ct < 8; ++ct) acc[rt][ct] = (f32x4){0.f,0.f,0.f,0.f};
    float csum[8] = {0.f,0.f,0.f,0.f,0.f,0.f,0.f,0.f};

    const int swzl = 8*(l&7);
    for (int tile = 0; tile < 16; ++tile) {
        const float* xt = xbase + tile*64;
        #pragma unroll
        for (int i = 0; i < 8; ++i) {
            int f4 = t + 256*i;
            int c = f4 >> 4, s0 = (f4 & 15)*4;
            float4 v = *(const float4*)(xt + (size_t)c*HW + s0);
            csum[i] += v.x + v.y + v.z + v.w;
            uint2 pk; pk.x = pack2(v.x, v.y); pk.y = pack2(v.z, v.w);
            *(uint2*)&xbS[c*64 + (s0 ^ (8*(c&7)))] = pk;
        }
        __syncthreads();
        #pragma unroll
        for (int ks = 0; ks < 2; ++ks) {
            const int sidx = (ks*32 + 8*lg) ^ swzl;
            short8 af0 = *(const short8*)&xbS[(32*wid      + lm)*64 + sidx];
            short8 af1 = *(const short8*)&xbS[(32*wid + 16 + lm)*64 + sidx];
            #pragma unroll
            for (int ct = 0; ct < 8; ++ct) {
                short8 bf = *(const short8*)&xbS[(ct*16 + lm)*64 + sidx];
                acc[0][ct] = __builtin_amdgcn_mfma_f32_16x16x32_bf16(af0, bf, acc[0][ct], 0,0,0);
                acc[1][ct] = __builtin_amdgcn_mfma_f32_16x16x32_bf16(af1, bf, acc[1][ct], 0,0,0);
            }
        }
        __syncthreads();
    }
    // write M partials
    float* M = ws + WS_M + n*16384;
    #pragma unroll
    for (int rt = 0; rt < 2; ++rt)
        #pragma unroll
        for (int ct = 0; ct < 8; ++ct)
            #pragma unroll
            for (int r = 0; r < 4; ++r) {
                int row = 32*wid + 16*rt + 4*lg + r;
                atomicAdd(&M[row*128 + ct*16 + lm], acc[rt][ct][r]);
            }
    // column sums: thread's c set = (t>>4) + 16*i; reduce across 16 lanes (l&15)
    #pragma unroll
    for (int i = 0; i < 8; ++i) {
        float v = csum[i];
        v += __shfl_xor(v, 1); v += __shfl_xor(v, 2);
        v += __shfl_xor(v, 4); v += __shfl_xor(v, 8);
        if (lm == 0) atomicAdd(ws + WS_CS + n*128 + (t>>4) + 16*i, v);
    }
}

// --------------------------- K2: stats finalize: Q = diag(W1 M W1^T), affine
// grid 40: (n, o-quarter of 32)
__global__ __launch_bounds__(256) void k2_final(const float* __restrict__ W1,
        const float* __restrict__ b1, const float* __restrict__ gnw,
        const float* __restrict__ gnb, float* ws) {
    __shared__ __align__(16) float W1l[32*132];
    __shared__ float sumH[32], sumH2[32], mug[2], rsg[2];
    const int t = threadIdx.x, b = blockIdx.x;
    const int n = b >> 2, q = b & 3, o0 = q*32;
    #pragma unroll
    for (int i = 0; i < 4; ++i) {
        int fi = t + 256*i;                 // 1024 float4s
        int row = fi >> 5, c4 = (fi & 31)*4;
        *(float4*)&W1l[row*132 + c4] = *(const float4*)(W1 + (size_t)(o0+row)*128 + c4);
    }
    __syncthreads();
    const int ol = t >> 3, kk = t & 7, o = o0 + ol;
    const float* wrow = &W1l[ol*132];
    const float* cs = ws + WS_CS + n*128;
    const float* M = ws + WS_M + n*16384;
    float S1p = 0.f, Qp = 0.f;
    #pragma unroll 4
    for (int j = 0; j < 16; ++j) { int kc = kk*16 + j; S1p = fmaf(wrow[kc], cs[kc], S1p); }
    for (int k = 0; k < 128; ++k) {
        float wk = wrow[k];
        const float* mrow = M + k*128 + kk*16;
        float inner = 0.f;
        #pragma unroll
        for (int j4 = 0; j4 < 4; ++j4) {
            float4 m = *(const float4*)(mrow + 4*j4);
            const float* wv = wrow + kk*16 + 4*j4;
            inner += m.x*wv[0] + m.y*wv[1] + m.z*wv[2] + m.w*wv[3];
        }
        Qp = fmaf(wk, inner, Qp);
    }
    S1p += __shfl_xor(S1p, 1); S1p += __shfl_xor(S1p, 2); S1p += __shfl_xor(S1p, 4);
    Qp  += __shfl_xor(Qp, 1);  Qp  += __shfl_xor(Qp, 2);  Qp  += __shfl_xor(Qp, 4);
    if (kk == 0) {
        float bv = b1[o];
        sumH[ol]  = S1p + 65536.f*bv;
        sumH2[ol] = Qp + 2.f*bv*S1p + 65536.f*bv*bv;
    }
    __syncthreads();
    if (t < 2) {
        float sh = 0.f, sh2 = 0.f;
        for (int i = 0; i < 16; ++i) { sh += sumH[t*16+i]; sh2 += sumH2[t*16+i]; }
        float mu = sh * (1.f/1048576.f);
        float var = sh2 * (1.f/1048576.f) - mu*mu;
        mug[t] = mu; rsg[t] = rsqrtf(var + 1e-5f);
    }
    __syncthreads();
    if (t < 32) {
        int oo = o0 + t, g = t >> 4;
        float a = rsg[g]*gnw[oo];
        ws[WS_A  + n*128 + oo] = a;
        ws[WS_CC + n*128 + oo] = gnb[oo] + (b1[oo] - mug[g])*a;
    }
}

// ---------------- K3: fused conv1->GN->GELU->conv2->feats + Gram + row LSE
__global__ __launch_bounds__(256) void k3_fused(const float* __restrict__ x,
        float* ws, const float* __restrict__ b2v, const float* __restrict__ temp,
        float* __restrict__ out) {
    __shared__ __align__(16) ushort shm[16384];   // xfT [64][128] | gT [64][128]
    ushort* xfT = shm;
    ushort* gT  = shm + 8192;
    const int t = threadIdx.x, b = blockIdx.x;
    const int n = b >> 10, widx = b & 1023;
    const int h0 = (widx >> 5)*8, w0 = (widx & 31)*8;
    const int l = t & 63, wid = t >> 6;
    const int lm = l & 15, lg = l >> 4;
    const int swzl = 8*(l&7);
    const ushort* w1b = (const ushort*)(ws + WS_W1BF);
    const ushort* w2b = (const ushort*)(ws + WS_W2BF);
    const float* xb = x + (size_t)n*CH*HW + (size_t)h0*IMGW + w0;

    // ---- stage: fp32 window -> 4x4 shfl transpose -> bf16 LDS [p][c^swz(p)]
    const int p0 = 4*lm;
    const int dy = p0 >> 3, dx0 = p0 & 7;
    #pragma unroll
    for (int i = 0; i < 8; ++i) {
        const int cb = 4*wid + 16*i;        // c base of this 4x4 group
        const int c  = cb + lg;
        float r0, r1, r2, r3;
        { float4 v = *(const float4*)(xb + (size_t)c*HW + dy*IMGW + dx0);
          r0 = v.x; r1 = v.y; r2 = v.z; r3 = v.w; }
        // 4x4 transpose across lane groups (lg)
        { float s0v = (lg&2) ? r0 : r2, s1v = (lg&2) ? r1 : r3;
          float u0 = __shfl_xor(s0v, 32), u1 = __shfl_xor(s1v, 32);
          if (lg&2) { r0 = u0; r1 = u1; } else { r2 = u0; r3 = u1; }
          float sA = (lg&1) ? r0 : r1; float uA = __shfl_xor(sA, 16);
          if (lg&1) r0 = uA; else r1 = uA;
          float sB = (lg&1) ? r2 : r3; float uB = __shfl_xor(sB, 16);
          if (lg&1) r2 = uB; else r3 = uB; }
        const int p = p0 + lg;
        uint2 pk; pk.x = pack2(r0, r1); pk.y = pack2(r2, r3);
        *(uint2*)&xfT[p*128 + (cb ^ (8*(p&7)))] = pk;
    }
    __syncthreads();

    // ---- conv1: h = W1 * x  (per wave: 32 o-rows x 64 p)
    const int o0 = 32*wid;
    short8 af[2][4];
    #pragma unroll
    for (int ot = 0; ot < 2; ++ot)
        #pragma unroll
        for (int ks = 0; ks < 4; ++ks)
            af[ot][ks] = *(const short8*)(w1b + (size_t)(o0 + ot*16 + lm)*128 + ks*32 + 8*lg);
    f32x4 hacc[2][4];
    #pragma unroll
    for (int ot = 0; ot < 2; ++ot)
        #pragma unroll
        for (int pt = 0; pt < 4; ++pt) hacc[ot][pt] = (f32x4){0.f,0.f,0.f,0.f};
    #pragma unroll
    for (int ks = 0; ks < 4; ++ks)
        #pragma unroll
        for (int pt = 0; pt < 4; ++pt) {
            short8 bfr = *(const short8*)&xfT[(pt*16 + lm)*128 + ((ks*32 + 8*lg) ^ swzl)];
            hacc[0][pt] = __builtin_amdgcn_mfma_f32_16x16x32_bf16(af[0][ks], bfr, hacc[0][pt], 0,0,0);
            hacc[1][pt] = __builtin_amdgcn_mfma_f32_16x16x32_bf16(af[1][ks], bfr, hacc[1][pt], 0,0,0);
        }

    // ---- GN affine + exact GELU -> gT [p][o^swz(p)]
    const float* aP = ws + WS_A  + n*128;
    const float* cP = ws + WS_CC + n*128;
    #pragma unroll
    for (int ot = 0; ot < 2; ++ot) {
        float av[4], cv[4];
        #pragma unroll
        for (int r = 0; r < 4; ++r) {
            int o = o0 + ot*16 + 4*lg + r;
            av[r] = aP[o]; cv[r] = cP[o];
        }
        #pragma unroll
        for (int pt = 0; pt < 4; ++pt) {
            f32x4 h = hacc[ot][pt];
            float g0, g1, g2, g3;
            { float hn = fmaf(h[0], av[0], cv[0]); g0 = 0.5f*hn*(1.f + erff(hn*0.70710678118654752f)); }
            { float hn = fmaf(h[1], av[1], cv[1]); g1 = 0.5f*hn*(1.f + erff(hn*0.70710678118654752f)); }
            { float hn = fmaf(h[2], av[2], cv[2]); g2 = 0.5f*hn*(1.f + erff(hn*0.70710678118654752f)); }
            { float hn = fmaf(h[3], av[3], cv[3]); g3 = 0.5f*hn*(1.f + erff(hn*0.70710678118654752f)); }
            int p = pt*16 + lm;
            uint2 pk; pk.x = pack2(g0, g1); pk.y = pack2(g2, g3);
            *(uint2*)&gT[p*128 + ((o0 + ot*16 + 4*lg) ^ swzl)] = pk;
        }
    }
    __syncthreads();

    // ---- conv2: f = W2 * g + b2
    short8 af2[2][4];
    #pragma unroll
    for (int ot = 0; ot < 2; ++ot)
        #pragma unroll
        for (int ks = 0; ks < 4; ++ks)
            af2[ot][ks] = *(const short8*)(w2b + (size_t)(o0 + ot*16 + lm)*128 + ks*32 + 8*lg);
    f32x4 facc[2][4];
    #pragma unroll
    for (int ot = 0; ot < 2; ++ot)
        #pragma unroll
        for (int pt = 0; pt < 4; ++pt) facc[ot][pt] = (f32x4){0.f,0.f,0.f,0.f};
    #pragma unroll
    for (int ks = 0; ks < 4; ++ks)
        #pragma unroll
        for (int pt = 0; pt < 4; ++pt) {
            short8 bfr = *(const short8*)&gT[(pt*16 + lm)*128 + ((ks*32 + 8*lg) ^ swzl)];
            facc[0][pt] = __builtin_amdgcn_mfma_f32_16x16x32_bf16(af2[0][ks], bfr, facc[0][pt], 0,0,0);
            facc[1][pt] = __builtin_amdgcn_mfma_f32_16x16x32_bf16(af2[1][ks], bfr, facc[1][pt], 0,0,0);
        }

    // ---- feats write (fp32) + fT (bf16, reuse xfT buffer)
    float b2r[2][4];
    #pragma unroll
    for (int ot = 0; ot < 2; ++ot)
        #pragma unroll
        for (int r = 0; r < 4; ++r) b2r[ot][r] = b2v[o0 + ot*16 + 4*lg + r];
    #pragma unroll
    for (int ot = 0; ot < 2; ++ot)
        #pragma unroll
        for (int pt = 0; pt < 4; ++pt) {
            f32x4 f = facc[ot][pt];
            float f0 = f[0] + b2r[ot][0], f1 = f[1] + b2r[ot][1];
            float f2 = f[2] + b2r[ot][2], f3 = f[3] + b2r[ot][3];
            int p = pt*16 + lm;
            int py = p >> 3, px = p & 7;
            float* ob = out + (size_t)n*CH*HW + (size_t)(o0 + ot*16 + 4*lg)*HW
                            + (size_t)(h0 + py)*IMGW + w0 + px;
            ob[0] = f0; ob[HW] = f1; ob[2*HW] = f2; ob[3*HW] = f3;
            uint2 pk; pk.x = pack2(f0, f1); pk.y = pack2(f2, f3);
            *(uint2*)&xfT[p*128 + ((o0 + ot*16 + 4*lg) ^ swzl)] = pk;
        }
    __syncthreads();

    // ---- Gram: sim[p][q] = f_p . f_q (wave: rows [16*wid,16*wid+16) x all q)
    const float invT = 1.f / temp[0];
    f32x4 sacc[4];
    #pragma unroll
    for (int qt = 0; qt < 4; ++qt) sacc[qt] = (f32x4){0.f,0.f,0.f,0.f};
    const int pr0 = 16*wid;
    #pragma unroll
    for (int ks = 0; ks < 4; ++ks) {
        short8 afr = *(const short8*)&xfT[(pr0 + lm)*128 + ((ks*32 + 8*lg) ^ swzl)];
        #pragma unroll
        for (int qt = 0; qt < 4; ++qt) {
            short8 bfr = *(const short8*)&xfT[(qt*16 + lm)*128 + ((ks*32 + 8*lg) ^ swzl)];
            sacc[qt] = __builtin_amdgcn_mfma_f32_16x16x32_bf16(afr, bfr, sacc[qt], 0,0,0);
        }
    }

    // ---- row-wise LSE + loss partial (no sim materialization)
    float lossAcc = 0.f;
    #pragma unroll
    for (int r = 0; r < 4; ++r) {
        float v0 = sacc[0][r]*invT, v1 = sacc[1][r]*invT;
        float v2 = sacc[2][r]*invT, v3 = sacc[3][r]*invT;
        float m = fmaxf(fmaxf(v0, v1), fmaxf(v2, v3));
        m = fmaxf(m, __shfl_xor(m, 1)); m = fmaxf(m, __shfl_xor(m, 2));
        m = fmaxf(m, __shfl_xor(m, 4)); m = fmaxf(m, __shfl_xor(m, 8));
        float s = expf(v0-m) + expf(v1-m) + expf(v2-m) + expf(v3-m);
        s += __shfl_xor(s, 1); s += __shfl_xor(s, 2);
        s += __shfl_xor(s, 4); s += __shfl_xor(s, 8);
        float lse = m + logf(s);
        if (lm == 4*lg + r) {
            float dv = (wid == 0) ? v0 : (wid == 1) ? v1 : (wid == 2) ? v2 : v3;
            lossAcc += lse - dv;
        }
    }
    lossAcc += __shfl_xor(lossAcc, 1);  lossAcc += __shfl_xor(lossAcc, 2);
    lossAcc += __shfl_xor(lossAcc, 4);  lossAcc += __shfl_xor(lossAcc, 8);
    lossAcc += __shfl_xor(lossAcc, 16); lossAcc += __shfl_xor(lossAcc, 32);
    if (l == 0) ws[WS_LOSS + b*4 + wid] = lossAcc;
}

// ------------------------------------------ K4: deterministic loss reduction
__global__ void k4_loss(const float* __restrict__ ws, float* __restrict__ out) {
    __shared__ float red[4];
    int t = threadIdx.x;
    float s = 0.f;
    for (int i = t; i < 40960; i += 256) s += ws[WS_LOSS + i];
    #pragma unroll
    for (int off = 32; off > 0; off >>= 1) s += __shfl_down(s, off, 64);
    if ((t & 63) == 0) red[t >> 6] = s;
    __syncthreads();
    if (t == 0) out[FEATS_ELEMS] = (red[0] + red[1] + red[2] + red[3]) * (1.f/655360.f);
}

// ---------------------------------------------------------------- launcher
extern "C" void kernel_launch(void* const* d_in, const int* in_sizes, int n_in,
                              void* d_out, int out_size, void* d_ws, size_t ws_size,
                              hipStream_t stream) {
    (void)in_sizes; (void)n_in; (void)out_size; (void)ws_size;
    const float* x    = (const float*)d_in[0];
    const float* W1   = (const float*)d_in[1];
    const float* b1   = (const float*)d_in[2];
    const float* gnw  = (const float*)d_in[3];
    const float* gnb  = (const float*)d_in[4];
    const float* W2   = (const float*)d_in[5];
    const float* b2   = (const float*)d_in[6];
    const float* temp = (const float*)d_in[7];
    float* out = (float*)d_out;
    float* ws  = (float*)d_ws;

    hipLaunchKernelGGL(k0_init,  dim3(709),  dim3(256), 0, stream, W1, W2, ws);
    hipLaunchKernelGGL(k1_syrk,  dim3(640),  dim3(256), 0, stream, x, ws);
    hipLaunchKernelGGL(k2_final, dim3(40),   dim3(256), 0, stream, W1, b1, gnw, gnb, ws);
    hipLaunchKernelGGL(k3_fused, dim3(NWIN), dim3(256), 0, stream, x, ws, b2, temp, out);
    hipLaunchKernelGGL(k4_loss,  dim3(1),    dim3(256), 0, stream, ws, out);
}

// Round 3
// 493.059 us; speedup vs baseline: 3.0221x; 1.2320x over previous
//
#include <hip/hip_runtime.h>
#include <hip/hip_bf16.h>
#include <math.h>

#define CH 128
#define IMGW 256
#define NIMG 10
#define HW 65536
#define FEATS_ELEMS ((size_t)NIMG*CH*HW)

typedef __attribute__((ext_vector_type(8))) short short8;
typedef __attribute__((ext_vector_type(4))) float f32x4;

// workspace layout (float offsets)
#define WS_W1BF 0          // W1 bf16 [128 o][128 c]
#define WS_W2BF 8192
#define WS_SUM  16384      // [10][8] group sums of h
#define WS_SQ   16464      // [10][8] group sums of h^2
#define WS_A    16544      // [10][128] rsig*gn_w
#define WS_CC   17824      // [10][128] gnb + (b1-mu)*a
#define WS_LOSS 19104      // [5120*8] per-(block,wave) loss partials

static __device__ __forceinline__ ushort f2bf(float f) {
    __hip_bfloat16 h = __float2bfloat16(f);
    return *reinterpret_cast<ushort*>(&h);
}
static __device__ __forceinline__ uint pack2(float a, float b) {
    return (uint)f2bf(a) | ((uint)f2bf(b) << 16);
}
static __device__ __forceinline__ float gelu_fast(float v) {
    // x * sigmoid(2*0.79788456*(x + 0.044715 x^3)); max abs err ~3e-4
    float v2 = v*v;
    float z2 = v * fmaf(0.07135481627f, v2, 1.59576912161f);
    return v / (1.0f + __expf(-z2));
}

// 4x4 cross-lane transpose among lanes {l, l^16, l^32, l^48}.
// In: lane lg holds 4 consecutive "inner" values (r0..r3) of its own outer idx.
// Out: lane lg holds inner idx lg's 4 outer values.
static __device__ __forceinline__ void xpose4(int lg, float& r0, float& r1,
                                              float& r2, float& r3) {
    float s0v = (lg&2) ? r0 : r2, s1v = (lg&2) ? r1 : r3;
    float u0 = __shfl_xor(s0v, 32), u1 = __shfl_xor(s1v, 32);
    if (lg&2) { r0 = u0; r1 = u1; } else { r2 = u0; r3 = u1; }
    float sA = (lg&1) ? r0 : r1; float uA = __shfl_xor(sA, 16);
    if (lg&1) r0 = uA; else r1 = uA;
    float sB = (lg&1) ? r2 : r3; float uB = __shfl_xor(sB, 16);
    if (lg&1) r2 = uB; else r3 = uB;
}

// ------------------------------------------------ K0: W->bf16, zero stats
__global__ void k0_init(const float* __restrict__ W1, const float* __restrict__ W2,
                        float* __restrict__ ws) {
    int idx = blockIdx.x*256 + threadIdx.x;     // 0..16383
    uint* w1b = (uint*)(ws + WS_W1BF);
    uint* w2b = (uint*)(ws + WS_W2BF);
    if (idx < 8192) {
        w1b[idx] = pack2(W1[2*idx], W1[2*idx+1]);
    } else {
        int j = idx - 8192;
        w2b[j] = pack2(W2[2*j], W2[2*j+1]);
    }
    if (blockIdx.x == 0 && threadIdx.x < 160) ws[WS_SUM + threadIdx.x] = 0.0f;
}

// ------------------- K1: conv1 via MFMA on coalesced chunks -> group stats
// grid 640: (n, 64 chunks of 1024 spatial). h discarded; only sum/sumsq kept.
__global__ __launch_bounds__(256) void k1_stats(const float* __restrict__ x,
                                                float* ws,
                                                const float* __restrict__ b1) {
    __shared__ __align__(16) ushort xT[64*128];      // [p 64][c 128] bf16
    const int t = threadIdx.x, b = blockIdx.x;
    const int n = b >> 6, chunk = b & 63;
    const int l = t & 63, wid = t >> 6;
    const int lm = l & 15, lg = l >> 4;
    const ushort* w1b = (const ushort*)(ws + WS_W1BF);
    const int o0 = 32*wid;

    short8 af[2][4];
    #pragma unroll
    for (int ot = 0; ot < 2; ++ot)
        #pragma unroll
        for (int ks = 0; ks < 4; ++ks)
            af[ot][ks] = *(const short8*)(w1b + (size_t)(o0 + ot*16 + lm)*128 + ks*32 + 8*lg);
    float bv[2][4];
    #pragma unroll
    for (int ot = 0; ot < 2; ++ot)
        #pragma unroll
        for (int r = 0; r < 4; ++r) bv[ot][r] = b1[o0 + ot*16 + 4*lg + r];

    const float* xb = x + (size_t)n*CH*HW + chunk*1024;
    float s1[2] = {0.f, 0.f}, s2[2] = {0.f, 0.f};
    const int swzl = 8*(lm&7);

    for (int tile = 0; tile < 16; ++tile) {
        const float* xt = xb + tile*64;
        #pragma unroll
        for (int i = 0; i < 8; ++i) {
            int gc = wid*8 + i;                 // c-quad index 0..31
            int c = 4*gc + lg;
            float4 v = *(const float4*)(xt + (size_t)c*HW + 4*lm);
            float r0 = v.x, r1 = v.y, r2 = v.z, r3 = v.w;
            xpose4(lg, r0, r1, r2, r3);
            int p = 4*lm + lg;
            uint2 pk; pk.x = pack2(r0, r1); pk.y = pack2(r2, r3);
            *(uint2*)&xT[p*128 + ((4*gc) ^ (8*(p&7)))] = pk;
        }
        __syncthreads();
        f32x4 hacc[2][4];
        #pragma unroll
        for (int ot = 0; ot < 2; ++ot)
            #pragma unroll
            for (int pt = 0; pt < 4; ++pt)
                hacc[ot][pt] = (f32x4){bv[ot][0], bv[ot][1], bv[ot][2], bv[ot][3]};
        #pragma unroll
        for (int ks = 0; ks < 4; ++ks)
            #pragma unroll
            for (int pt = 0; pt < 4; ++pt) {
                short8 bfr = *(const short8*)&xT[(pt*16 + lm)*128 + ((ks*32 + 8*lg) ^ swzl)];
                hacc[0][pt] = __builtin_amdgcn_mfma_f32_16x16x32_bf16(af[0][ks], bfr, hacc[0][pt], 0,0,0);
                hacc[1][pt] = __builtin_amdgcn_mfma_f32_16x16x32_bf16(af[1][ks], bfr, hacc[1][pt], 0,0,0);
            }
        __syncthreads();
        #pragma unroll
        for (int ot = 0; ot < 2; ++ot)
            #pragma unroll
            for (int pt = 0; pt < 4; ++pt)
                #pragma unroll
                for (int r = 0; r < 4; ++r) {
                    float h = hacc[ot][pt][r];
                    s1[ot] += h; s2[ot] += h*h;
                }
    }
    #pragma unroll
    for (int ot = 0; ot < 2; ++ot) {
        float a = s1[ot], q = s2[ot];
        #pragma unroll
        for (int off = 1; off < 64; off <<= 1) {
            a += __shfl_xor(a, off); q += __shfl_xor(q, off);
        }
        if (l == 0) {
            int g = n*8 + 2*wid + ot;
            atomicAdd(&ws[WS_SUM + g], a);
            atomicAdd(&ws[WS_SQ  + g], q);
        }
    }
}

// ----------------------------------------------- K2: finalize affine factors
__global__ void k2_final(const float* __restrict__ b1, const float* __restrict__ gnw,
                         const float* __restrict__ gnb, float* ws) {
    __shared__ float muS[80], rsS[80];
    int t = threadIdx.x;
    if (t < 80) {
        const float inv = 1.0f/1048576.0f;       // 16ch * 65536
        float mu  = ws[WS_SUM + t] * inv;
        float var = ws[WS_SQ  + t] * inv - mu*mu;
        muS[t] = mu;
        rsS[t] = rsqrtf(var + 1e-5f);
    }
    __syncthreads();
    for (int idx = t; idx < 1280; idx += 256) {
        int n = idx >> 7, o = idx & 127;
        int g = n*8 + (o >> 4);
        float a = rsS[g]*gnw[o];
        ws[WS_A  + idx] = a;
        ws[WS_CC + idx] = gnb[o] + (b1[o] - muS[g])*a;
    }
}

// ---- K3: 2-window strip (8 rows x 16 cols), 8 waves. conv1->GN->GELU->conv2
//      -> feats store + per-window Gram + row LSE. Waves: win = wid>>2,
//      o-quarter/gram-quarter = wid&3.
__global__ __launch_bounds__(512, 4) void k3_fused(const float* __restrict__ x,
        float* ws, const float* __restrict__ b2v, const float* __restrict__ temp,
        float* __restrict__ out) {
    __shared__ __align__(16) ushort xT[128*128];   // x^T then f^T  (32 KB)
    __shared__ __align__(16) ushort gT[128*128];   // g^T           (32 KB)
    const int t = threadIdx.x, b = blockIdx.x;
    const int n = b >> 9, strip = b & 511;
    const int h0 = (strip >> 4)*8, w0c = (strip & 15)*16;
    const int l = t & 63, wid = t >> 6;
    const int lm = l & 15, lg = l >> 4;
    const int swzl = 8*(lm&7);
    const ushort* w1b = (const ushort*)(ws + WS_W1BF);
    const ushort* w2b = (const ushort*)(ws + WS_W2BF);

    // ---- stage strip: fp32 -> 4x4 shfl transpose -> bf16 xT[p][c^swz]
    {
        const float* xb = x + (size_t)n*CH*HW + (size_t)h0*IMGW + w0c;
        const int q = lm & 3, dy = (lm >> 2) + 4*(wid >> 2);
        #pragma unroll
        for (int i = 0; i < 8; ++i) {
            int gc = (wid & 3)*8 + i;           // c-quad 0..31
            int c = 4*gc + lg;
            float4 v = *(const float4*)(xb + (size_t)c*HW + dy*IMGW + 4*q);
            float r0 = v.x, r1 = v.y, r2 = v.z, r3 = v.w;
            xpose4(lg, r0, r1, r2, r3);
            int col = 4*q + lg;                  // strip col 0..15
            int p = (col >> 3)*64 + dy*8 + (col & 7);
            uint2 pk; pk.x = pack2(r0, r1); pk.y = pack2(r2, r3);
            *(uint2*)&xT[p*128 + ((4*gc) ^ (8*(p&7)))] = pk;
        }
    }
    __syncthreads();

    const int win = wid >> 2, ow = wid & 3;
    const int o0 = 32*ow, pB = win*64;

    // ---- conv1
    short8 af[2][4];
    #pragma unroll
    for (int ot = 0; ot < 2; ++ot)
        #pragma unroll
        for (int ks = 0; ks < 4; ++ks)
            af[ot][ks] = *(const short8*)(w1b + (size_t)(o0 + ot*16 + lm)*128 + ks*32 + 8*lg);
    f32x4 hacc[2][4];
    #pragma unroll
    for (int ot = 0; ot < 2; ++ot)
        #pragma unroll
        for (int pt = 0; pt < 4; ++pt) hacc[ot][pt] = (f32x4){0.f,0.f,0.f,0.f};
    #pragma unroll
    for (int ks = 0; ks < 4; ++ks)
        #pragma unroll
        for (int pt = 0; pt < 4; ++pt) {
            short8 bfr = *(const short8*)&xT[(pB + pt*16 + lm)*128 + ((ks*32 + 8*lg) ^ swzl)];
            hacc[0][pt] = __builtin_amdgcn_mfma_f32_16x16x32_bf16(af[0][ks], bfr, hacc[0][pt], 0,0,0);
            hacc[1][pt] = __builtin_amdgcn_mfma_f32_16x16x32_bf16(af[1][ks], bfr, hacc[1][pt], 0,0,0);
        }

    // ---- GN affine + fast GELU -> gT[p][o^swz]
    {
        const float* aP = ws + WS_A  + n*128;
        const float* cP = ws + WS_CC + n*128;
        #pragma unroll
        for (int ot = 0; ot < 2; ++ot) {
            float av[4], cv[4];
            #pragma unroll
            for (int r = 0; r < 4; ++r) {
                int o = o0 + ot*16 + 4*lg + r;
                av[r] = aP[o]; cv[r] = cP[o];
            }
            #pragma unroll
            for (int pt = 0; pt < 4; ++pt) {
                f32x4 h = hacc[ot][pt];
                float g0 = gelu_fast(fmaf(h[0], av[0], cv[0]));
                float g1 = gelu_fast(fmaf(h[1], av[1], cv[1]));
                float g2 = gelu_fast(fmaf(h[2], av[2], cv[2]));
                float g3 = gelu_fast(fmaf(h[3], av[3], cv[3]));
                int p = pB + pt*16 + lm;
                uint2 pk; pk.x = pack2(g0, g1); pk.y = pack2(g2, g3);
                *(uint2*)&gT[p*128 + ((o0 + ot*16 + 4*lg) ^ swzl)] = pk;
            }
        }
    }
    __syncthreads();

    // ---- conv2
    short8 af2[2][4];
    #pragma unroll
    for (int ot = 0; ot < 2; ++ot)
        #pragma unroll
        for (int ks = 0; ks < 4; ++ks)
            af2[ot][ks] = *(const short8*)(w2b + (size_t)(o0 + ot*16 + lm)*128 + ks*32 + 8*lg);
    f32x4 facc[2][4];
    #pragma unroll
    for (int ot = 0; ot < 2; ++ot)
        #pragma unroll
        for (int pt = 0; pt < 4; ++pt) facc[ot][pt] = (f32x4){0.f,0.f,0.f,0.f};
    #pragma unroll
    for (int ks = 0; ks < 4; ++ks)
        #pragma unroll
        for (int pt = 0; pt < 4; ++pt) {
            short8 bfr = *(const short8*)&gT[(pB + pt*16 + lm)*128 + ((ks*32 + 8*lg) ^ swzl)];
            facc[0][pt] = __builtin_amdgcn_mfma_f32_16x16x32_bf16(af2[0][ks], bfr, facc[0][pt], 0,0,0);
            facc[1][pt] = __builtin_amdgcn_mfma_f32_16x16x32_bf16(af2[1][ks], bfr, facc[1][pt], 0,0,0);
        }

    // ---- feats store (fp32) + f^T (bf16) into xT
    {
        float b2r[2][4];
        #pragma unroll
        for (int ot = 0; ot < 2; ++ot)
            #pragma unroll
            for (int r = 0; r < 4; ++r) b2r[ot][r] = b2v[o0 + ot*16 + 4*lg + r];
        #pragma unroll
        for (int ot = 0; ot < 2; ++ot)
            #pragma unroll
            for (int pt = 0; pt < 4; ++pt) {
                f32x4 f = facc[ot][pt];
                float f0 = f[0] + b2r[ot][0], f1 = f[1] + b2r[ot][1];
                float f2 = f[2] + b2r[ot][2], f3 = f[3] + b2r[ot][3];
                int p = pt*16 + lm;              // window-local 0..63
                int py = p >> 3, px = p & 7;
                float* ob = out + (size_t)n*CH*HW + (size_t)(o0 + ot*16 + 4*lg)*HW
                                + (size_t)(h0 + py)*IMGW + w0c + win*8 + px;
                ob[0] = f0; ob[HW] = f1; ob[2*HW] = f2; ob[3*HW] = f3;
                uint2 pk; pk.x = pack2(f0, f1); pk.y = pack2(f2, f3);
                *(uint2*)&xT[(pB + p)*128 + ((o0 + ot*16 + 4*lg) ^ swzl)] = pk;
            }
    }
    __syncthreads();

    // ---- Gram (per window): rows [16*ow,16*ow+16) x all 64 q
    const float invT = 1.f / temp[0];
    f32x4 sacc[4];
    #pragma unroll
    for (int qt = 0; qt < 4; ++qt) sacc[qt] = (f32x4){0.f,0.f,0.f,0.f};
    #pragma unroll
    for (int ks = 0; ks < 4; ++ks) {
        short8 afr = *(const short8*)&xT[(pB + 16*ow + lm)*128 + ((ks*32 + 8*lg) ^ swzl)];
        #pragma unroll
        for (int qt = 0; qt < 4; ++qt) {
            short8 bfr = *(const short8*)&xT[(pB + qt*16 + lm)*128 + ((ks*32 + 8*lg) ^ swzl)];
            sacc[qt] = __builtin_amdgcn_mfma_f32_16x16x32_bf16(afr, bfr, sacc[qt], 0,0,0);
        }
    }

    // ---- row LSE + loss partial
    float lossAcc = 0.f;
    #pragma unroll
    for (int r = 0; r < 4; ++r) {
        float v0 = sacc[0][r]*invT, v1 = sacc[1][r]*invT;
        float v2 = sacc[2][r]*invT, v3 = sacc[3][r]*invT;
        float m = fmaxf(fmaxf(v0, v1), fmaxf(v2, v3));
        m = fmaxf(m, __shfl_xor(m, 1)); m = fmaxf(m, __shfl_xor(m, 2));
        m = fmaxf(m, __shfl_xor(m, 4)); m = fmaxf(m, __shfl_xor(m, 8));
        float s = __expf(v0-m) + __expf(v1-m) + __expf(v2-m) + __expf(v3-m);
        s += __shfl_xor(s, 1); s += __shfl_xor(s, 2);
        s += __shfl_xor(s, 4); s += __shfl_xor(s, 8);
        float lse = m + logf(s);
        if (lm == 4*lg + r) {
            float dv = (ow == 0) ? v0 : (ow == 1) ? v1 : (ow == 2) ? v2 : v3;
            lossAcc += lse - dv;
        }
    }
    lossAcc += __shfl_xor(lossAcc, 1);  lossAcc += __shfl_xor(lossAcc, 2);
    lossAcc += __shfl_xor(lossAcc, 4);  lossAcc += __shfl_xor(lossAcc, 8);
    lossAcc += __shfl_xor(lossAcc, 16); lossAcc += __shfl_xor(lossAcc, 32);
    if (l == 0) ws[WS_LOSS + b*8 + wid] = lossAcc;
}

// ------------------------------------------ K4: deterministic loss reduction
__global__ void k4_loss(const float* __restrict__ ws, float* __restrict__ out) {
    __shared__ float red[4];
    int t = threadIdx.x;
    float s = 0.f;
    for (int i = t; i < 40960; i += 256) s += ws[WS_LOSS + i];
    #pragma unroll
    for (int off = 32; off > 0; off >>= 1) s += __shfl_down(s, off, 64);
    if ((t & 63) == 0) red[t >> 6] = s;
    __syncthreads();
    if (t == 0) out[FEATS_ELEMS] = (red[0] + red[1] + red[2] + red[3]) * (1.f/655360.f);
}

// ---------------------------------------------------------------- launcher
extern "C" void kernel_launch(void* const* d_in, const int* in_sizes, int n_in,
                              void* d_out, int out_size, void* d_ws, size_t ws_size,
                              hipStream_t stream) {
    (void)in_sizes; (void)n_in; (void)out_size; (void)ws_size;
    const float* x    = (const float*)d_in[0];
    const float* W1   = (const float*)d_in[1];
    const float* b1   = (const float*)d_in[2];
    const float* gnw  = (const float*)d_in[3];
    const float* gnb  = (const float*)d_in[4];
    const float* W2   = (const float*)d_in[5];
    const float* b2   = (const float*)d_in[6];
    const float* temp = (const float*)d_in[7];
    float* out = (float*)d_out;
    float* ws  = (float*)d_ws;

    hipLaunchKernelGGL(k0_init,  dim3(64),   dim3(256), 0, stream, W1, W2, ws);
    hipLaunchKernelGGL(k1_stats, dim3(640),  dim3(256), 0, stream, x, ws, b1);
    hipLaunchKernelGGL(k2_final, dim3(1),    dim3(256), 0, stream, b1, gnw, gnb, ws);
    hipLaunchKernelGGL(k3_fused, dim3(5120), dim3(512), 0, stream, x, ws, b2, temp, out);
    hipLaunchKernelGGL(k4_loss,  dim3(1),    dim3(256), 0, stream, ws, out);
}

// Round 4
// 454.331 us; speedup vs baseline: 3.2797x; 1.0852x over previous
//
#include <hip/hip_runtime.h>
#include <hip/hip_bf16.h>
#include <math.h>

#define CH 128
#define IMGW 256
#define NIMG 10
#define HW 65536
#define FEATS_ELEMS ((size_t)NIMG*CH*HW)

typedef __attribute__((ext_vector_type(8))) short short8;
typedef __attribute__((ext_vector_type(4))) float f32x4;

// workspace layout (float offsets)
#define WS_W1BF 0          // W1 bf16 [128 o][128 c]
#define WS_W2BF 8192
#define WS_PART 16384      // primary: [5120][16] block stat partials; fallback: [160] atomic stats
#define WS_A    98304      // [10][128] rsig*gn_w
#define WS_CC   99584      // [10][128] affine constant
#define WS_LOSS 100864     // [5120*8] per-(block,wave) loss partials
#define WS_HT   141824     // h cache: 5120 strips * 8192 floats (16384 bf16)
#define NEED_FLOATS (141824 + 5120*8192)

static __device__ __forceinline__ ushort f2bf(float f) {
    __hip_bfloat16 h = __float2bfloat16(f);
    return *reinterpret_cast<ushort*>(&h);
}
static __device__ __forceinline__ uint pack2(float a, float b) {
    return (uint)f2bf(a) | ((uint)f2bf(b) << 16);
}
static __device__ __forceinline__ float gelu_fast(float v) {
    float v2 = v*v;
    float z2 = v * fmaf(0.07135481627f, v2, 1.59576912161f);
    return v / (1.0f + __expf(-z2));
}
// 4x4 cross-lane transpose among lanes {l, l^16, l^32, l^48}
static __device__ __forceinline__ void xpose4(int lg, float& r0, float& r1,
                                              float& r2, float& r3) {
    float s0v = (lg&2) ? r0 : r2, s1v = (lg&2) ? r1 : r3;
    float u0 = __shfl_xor(s0v, 32), u1 = __shfl_xor(s1v, 32);
    if (lg&2) { r0 = u0; r1 = u1; } else { r2 = u0; r3 = u1; }
    float sA = (lg&1) ? r0 : r1; float uA = __shfl_xor(sA, 16);
    if (lg&1) r0 = uA; else r1 = uA;
    float sB = (lg&1) ? r2 : r3; float uB = __shfl_xor(sB, 16);
    if (lg&1) r2 = uB; else r3 = uB;
}

// ------------------------------------------------ K0: W->bf16, zero fb stats
__global__ void k0_init(const float* __restrict__ W1, const float* __restrict__ W2,
                        float* __restrict__ ws) {
    int idx = blockIdx.x*256 + threadIdx.x;     // 0..16383
    uint* w1b = (uint*)(ws + WS_W1BF);
    uint* w2b = (uint*)(ws + WS_W2BF);
    if (idx < 8192) {
        w1b[idx] = pack2(W1[2*idx], W1[2*idx+1]);
    } else {
        int j = idx - 8192;
        w2b[j] = pack2(W2[2*j], W2[2*j+1]);
    }
    if (blockIdx.x == 0 && threadIdx.x < 160) ws[WS_PART + threadIdx.x] = 0.0f;
}

// ============================ PRIMARY PATH (h cached in ws) ============================

// K1: stage x strip -> conv1(+b1) -> stats partials -> store h^T (bf16, swizzled)
__global__ __launch_bounds__(512, 8) void k1_cache(const float* __restrict__ x,
        float* ws, const float* __restrict__ b1v) {
    __shared__ __align__(16) ushort xT[128*128];   // x^T then h^T  (32 KB)
    __shared__ float sp[32];
    const int t = threadIdx.x, b = blockIdx.x;
    const int n = b >> 9, strip = b & 511;
    const int h0 = (strip >> 4)*8, w0c = (strip & 15)*16;
    const int l = t & 63, wid = t >> 6;
    const int lm = l & 15, lg = l >> 4;
    const int swzl = 8*(lm&7);
    const ushort* w1b = (const ushort*)(ws + WS_W1BF);

    // ---- stage strip: fp32 -> 4x4 shfl transpose -> bf16 xT[p][c^swz]
    {
        const float* xb = x + (size_t)n*CH*HW + (size_t)h0*IMGW + w0c;
        const int q = lm & 3, dy = (lm >> 2) + 4*(wid >> 2);
        #pragma unroll
        for (int i = 0; i < 8; ++i) {
            int gc = (wid & 3)*8 + i;
            int c = 4*gc + lg;
            float4 v = *(const float4*)(xb + (size_t)c*HW + dy*IMGW + 4*q);
            float r0 = v.x, r1 = v.y, r2 = v.z, r3 = v.w;
            xpose4(lg, r0, r1, r2, r3);
            int col = 4*q + lg;
            int p = (col >> 3)*64 + dy*8 + (col & 7);
            uint2 pk; pk.x = pack2(r0, r1); pk.y = pack2(r2, r3);
            *(uint2*)&xT[p*128 + ((4*gc) ^ (8*(p&7)))] = pk;
        }
    }
    __syncthreads();

    const int win = wid >> 2, ow = wid & 3;
    const int o0 = 32*ow, pB = win*64;

    // ---- conv1 (h includes b1)
    short8 af[2][4];
    #pragma unroll
    for (int ot = 0; ot < 2; ++ot)
        #pragma unroll
        for (int ks = 0; ks < 4; ++ks)
            af[ot][ks] = *(const short8*)(w1b + (size_t)(o0 + ot*16 + lm)*128 + ks*32 + 8*lg);
    f32x4 hacc[2][4];
    #pragma unroll
    for (int ot = 0; ot < 2; ++ot) {
        float b0 = b1v[o0 + ot*16 + 4*lg + 0], c1 = b1v[o0 + ot*16 + 4*lg + 1];
        float c2 = b1v[o0 + ot*16 + 4*lg + 2], c3 = b1v[o0 + ot*16 + 4*lg + 3];
        #pragma unroll
        for (int pt = 0; pt < 4; ++pt) hacc[ot][pt] = (f32x4){b0, c1, c2, c3};
    }
    #pragma unroll
    for (int ks = 0; ks < 4; ++ks)
        #pragma unroll
        for (int pt = 0; pt < 4; ++pt) {
            short8 bfr = *(const short8*)&xT[(pB + pt*16 + lm)*128 + ((ks*32 + 8*lg) ^ swzl)];
            hacc[0][pt] = __builtin_amdgcn_mfma_f32_16x16x32_bf16(af[0][ks], bfr, hacc[0][pt], 0,0,0);
            hacc[1][pt] = __builtin_amdgcn_mfma_f32_16x16x32_bf16(af[1][ks], bfr, hacc[1][pt], 0,0,0);
        }

    // ---- stats: per-wave group sums -> sp
    float s1[2] = {0.f, 0.f}, s2[2] = {0.f, 0.f};
    #pragma unroll
    for (int ot = 0; ot < 2; ++ot)
        #pragma unroll
        for (int pt = 0; pt < 4; ++pt)
            #pragma unroll
            for (int r = 0; r < 4; ++r) {
                float h = hacc[ot][pt][r];
                s1[ot] += h; s2[ot] += h*h;
            }
    #pragma unroll
    for (int ot = 0; ot < 2; ++ot) {
        float a = s1[ot], q = s2[ot];
        #pragma unroll
        for (int off = 1; off < 64; off <<= 1) {
            a += __shfl_xor(a, off); q += __shfl_xor(q, off);
        }
        if (l == 0) { sp[wid*4 + ot*2] = a; sp[wid*4 + ot*2 + 1] = q; }
    }
    __syncthreads();   // sp ready; also: all conv1 xT reads complete

    if (t < 16) {
        int g = t & 7, which = t >> 3;
        int w0 = g >> 1, slot = (g & 1)*2 + which;
        float v = sp[w0*4 + slot] + sp[(4 + w0)*4 + slot];
        ws[WS_PART + (size_t)b*16 + which*8 + g] = v;
    }

    // ---- h^T write in-place into xT: [p][o^swz]
    #pragma unroll
    for (int ot = 0; ot < 2; ++ot)
        #pragma unroll
        for (int pt = 0; pt < 4; ++pt) {
            f32x4 h = hacc[ot][pt];
            int p = pB + pt*16 + lm;
            uint2 pk; pk.x = pack2(h[0], h[1]); pk.y = pack2(h[2], h[3]);
            *(uint2*)&xT[p*128 + ((o0 + ot*16 + 4*lg) ^ swzl)] = pk;
        }
    __syncthreads();

    // ---- stream LDS -> global h cache (verbatim, coalesced)
    const uint4* srcv = (const uint4*)xT;
    uint4* dstv = (uint4*)(ws + WS_HT + (size_t)b*8192);
    #pragma unroll
    for (int i = 0; i < 4; ++i) dstv[t + i*512] = srcv[t + i*512];
}

// K2 (primary): reduce block partials, finalize affine
__global__ void k2_cache(const float* __restrict__ gnw, const float* __restrict__ gnb,
                         float* ws) {
    __shared__ float sm[160];
    __shared__ float muS[80], rsS[80];
    const int t = threadIdx.x;
    if (t < 160) {
        int n = t >> 4, q = t & 15;
        const float* p = ws + WS_PART + (size_t)(n*512)*16 + q;
        float s = 0.f;
        for (int i = 0; i < 512; ++i) s += p[i*16];
        sm[t] = s;
    }
    __syncthreads();
    if (t < 80) {
        int n = t >> 3, g = t & 7;
        const float inv = 1.0f/1048576.0f;     // 16 ch * 65536 px
        float mu  = sm[n*16 + g]*inv;
        float var = sm[n*16 + 8 + g]*inv - mu*mu;
        muS[t] = mu; rsS[t] = rsqrtf(var + 1e-5f);
    }
    __syncthreads();
    for (int idx = t; idx < 1280; idx += 256) {
        int n = idx >> 7, o = idx & 127;
        int g = n*8 + (o >> 4);
        float a = rsS[g]*gnw[o];
        ws[WS_A  + idx] = a;
        ws[WS_CC + idx] = gnb[o] - muS[g]*a;   // b1 already inside h
    }
}

// K3 (primary): load h^T -> GN+GELU in place -> conv2 -> feats + Gram + LSE
__global__ __launch_bounds__(512, 8) void k3_consume(float* ws,
        const float* __restrict__ b2v, const float* __restrict__ temp,
        float* __restrict__ out) {
    __shared__ __align__(16) ushort fb[128*128];   // h -> g -> f  (32 KB)
    const int t = threadIdx.x, b = blockIdx.x;
    const int n = b >> 9, strip = b & 511;
    const int h0 = (strip >> 4)*8, w0c = (strip & 15)*16;
    const int l = t & 63, wid = t >> 6;
    const int lm = l & 15, lg = l >> 4;
    const int swzl = 8*(lm&7);
    const ushort* w2b = (const ushort*)(ws + WS_W2BF);

    // ---- load h strip (verbatim)
    {
        const uint4* srcv = (const uint4*)(ws + WS_HT + (size_t)b*8192);
        uint4* dstv = (uint4*)fb;
        #pragma unroll
        for (int i = 0; i < 4; ++i) dstv[t + i*512] = srcv[t + i*512];
    }
    __syncthreads();

    // ---- GN affine + GELU, in place (1:1 per-thread RMW)
    {
        uint2* hu = (uint2*)fb;
        const float* aP = ws + WS_A  + n*128;
        const float* cP = ws + WS_CC + n*128;
        #pragma unroll
        for (int i = 0; i < 8; ++i) {
            int c0 = t + i*512;
            int p = c0 >> 5;
            int o = ((c0 & 31)*4) ^ (8*(p&7));
            uint2 v = hu[c0];
            float hv0 = __uint_as_float((v.x & 0xffffu) << 16);
            float hv1 = __uint_as_float(v.x & 0xffff0000u);
            float hv2 = __uint_as_float((v.y & 0xffffu) << 16);
            float hv3 = __uint_as_float(v.y & 0xffff0000u);
            float g0 = gelu_fast(fmaf(hv0, aP[o],   cP[o]));
            float g1 = gelu_fast(fmaf(hv1, aP[o+1], cP[o+1]));
            float g2 = gelu_fast(fmaf(hv2, aP[o+2], cP[o+2]));
            float g3 = gelu_fast(fmaf(hv3, aP[o+3], cP[o+3]));
            uint2 pk; pk.x = pack2(g0, g1); pk.y = pack2(g2, g3);
            hu[c0] = pk;
        }
    }
    __syncthreads();

    const int win = wid >> 2, ow = wid & 3;
    const int o0 = 32*ow, pB = win*64;

    // ---- conv2
    short8 af2[2][4];
    #pragma unroll
    for (int ot = 0; ot < 2; ++ot)
        #pragma unroll
        for (int ks = 0; ks < 4; ++ks)
            af2[ot][ks] = *(const short8*)(w2b + (size_t)(o0 + ot*16 + lm)*128 + ks*32 + 8*lg);
    f32x4 facc[2][4];
    #pragma unroll
    for (int ot = 0; ot < 2; ++ot)
        #pragma unroll
        for (int pt = 0; pt < 4; ++pt) facc[ot][pt] = (f32x4){0.f,0.f,0.f,0.f};
    #pragma unroll
    for (int ks = 0; ks < 4; ++ks)
        #pragma unroll
        for (int pt = 0; pt < 4; ++pt) {
            short8 bfr = *(const short8*)&fb[(pB + pt*16 + lm)*128 + ((ks*32 + 8*lg) ^ swzl)];
            facc[0][pt] = __builtin_amdgcn_mfma_f32_16x16x32_bf16(af2[0][ks], bfr, facc[0][pt], 0,0,0);
            facc[1][pt] = __builtin_amdgcn_mfma_f32_16x16x32_bf16(af2[1][ks], bfr, facc[1][pt], 0,0,0);
        }
    __syncthreads();   // all g reads done before f overwrites

    // ---- feats store (fp32) + f^T (bf16) in place
    {
        float b2r[2][4];
        #pragma unroll
        for (int ot = 0; ot < 2; ++ot)
            #pragma unroll
            for (int r = 0; r < 4; ++r) b2r[ot][r] = b2v[o0 + ot*16 + 4*lg + r];
        #pragma unroll
        for (int ot = 0; ot < 2; ++ot)
            #pragma unroll
            for (int pt = 0; pt < 4; ++pt) {
                f32x4 f = facc[ot][pt];
                float f0 = f[0] + b2r[ot][0], f1 = f[1] + b2r[ot][1];
                float f2 = f[2] + b2r[ot][2], f3 = f[3] + b2r[ot][3];
                int p = pt*16 + lm;
                int py = p >> 3, px = p & 7;
                float* ob = out + (size_t)n*CH*HW + (size_t)(o0 + ot*16 + 4*lg)*HW
                                + (size_t)(h0 + py)*IMGW + w0c + win*8 + px;
                ob[0] = f0; ob[HW] = f1; ob[2*HW] = f2; ob[3*HW] = f3;
                uint2 pk; pk.x = pack2(f0, f1); pk.y = pack2(f2, f3);
                *(uint2*)&fb[(pB + p)*128 + ((o0 + ot*16 + 4*lg) ^ swzl)] = pk;
            }
    }
    __syncthreads();

    // ---- Gram (per window) + row LSE + loss partial
    const float invT = 1.f / temp[0];
    f32x4 sacc[4];
    #pragma unroll
    for (int qt = 0; qt < 4; ++qt) sacc[qt] = (f32x4){0.f,0.f,0.f,0.f};
    #pragma unroll
    for (int ks = 0; ks < 4; ++ks) {
        short8 afr = *(const short8*)&fb[(pB + 16*ow + lm)*128 + ((ks*32 + 8*lg) ^ swzl)];
        #pragma unroll
        for (int qt = 0; qt < 4; ++qt) {
            short8 bfr = *(const short8*)&fb[(pB + qt*16 + lm)*128 + ((ks*32 + 8*lg) ^ swzl)];
            sacc[qt] = __builtin_amdgcn_mfma_f32_16x16x32_bf16(afr, bfr, sacc[qt], 0,0,0);
        }
    }
    float lossAcc = 0.f;
    #pragma unroll
    for (int r = 0; r < 4; ++r) {
        float v0 = sacc[0][r]*invT, v1 = sacc[1][r]*invT;
        float v2 = sacc[2][r]*invT, v3 = sacc[3][r]*invT;
        float m = fmaxf(fmaxf(v0, v1), fmaxf(v2, v3));
        m = fmaxf(m, __shfl_xor(m, 1)); m = fmaxf(m, __shfl_xor(m, 2));
        m = fmaxf(m, __shfl_xor(m, 4)); m = fmaxf(m, __shfl_xor(m, 8));
        float s = __expf(v0-m) + __expf(v1-m) + __expf(v2-m) + __expf(v3-m);
        s += __shfl_xor(s, 1); s += __shfl_xor(s, 2);
        s += __shfl_xor(s, 4); s += __shfl_xor(s, 8);
        float lse = m + logf(s);
        if (lm == 4*lg + r) {
            float dv = (ow == 0) ? v0 : (ow == 1) ? v1 : (ow == 2) ? v2 : v3;
            lossAcc += lse - dv;
        }
    }
    lossAcc += __shfl_xor(lossAcc, 1);  lossAcc += __shfl_xor(lossAcc, 2);
    lossAcc += __shfl_xor(lossAcc, 4);  lossAcc += __shfl_xor(lossAcc, 8);
    lossAcc += __shfl_xor(lossAcc, 16); lossAcc += __shfl_xor(lossAcc, 32);
    if (l == 0) ws[WS_LOSS + (size_t)b*8 + wid] = lossAcc;
}

// ============================ FALLBACK PATH (round-3, ws too small) ============================

__global__ __launch_bounds__(256) void k1_fb(const float* __restrict__ x,
                                             float* ws, const float* __restrict__ b1) {
    __shared__ __align__(16) ushort xT[64*128];
    const int t = threadIdx.x, b = blockIdx.x;
    const int n = b >> 6, chunk = b & 63;
    const int l = t & 63, wid = t >> 6;
    const int lm = l & 15, lg = l >> 4;
    const ushort* w1b = (const ushort*)(ws + WS_W1BF);
    const int o0 = 32*wid;
    short8 af[2][4];
    #pragma unroll
    for (int ot = 0; ot < 2; ++ot)
        #pragma unroll
        for (int ks = 0; ks < 4; ++ks)
            af[ot][ks] = *(const short8*)(w1b + (size_t)(o0 + ot*16 + lm)*128 + ks*32 + 8*lg);
    float bv[2][4];
    #pragma unroll
    for (int ot = 0; ot < 2; ++ot)
        #pragma unroll
        for (int r = 0; r < 4; ++r) bv[ot][r] = b1[o0 + ot*16 + 4*lg + r];
    const float* xb = x + (size_t)n*CH*HW + chunk*1024;
    float s1[2] = {0.f, 0.f}, s2[2] = {0.f, 0.f};
    const int swzl = 8*(lm&7);
    for (int tile = 0; tile < 16; ++tile) {
        const float* xt = xb + tile*64;
        #pragma unroll
        for (int i = 0; i < 8; ++i) {
            int gc = wid*8 + i;
            int c = 4*gc + lg;
            float4 v = *(const float4*)(xt + (size_t)c*HW + 4*lm);
            float r0 = v.x, r1 = v.y, r2 = v.z, r3 = v.w;
            xpose4(lg, r0, r1, r2, r3);
            int p = 4*lm + lg;
            uint2 pk; pk.x = pack2(r0, r1); pk.y = pack2(r2, r3);
            *(uint2*)&xT[p*128 + ((4*gc) ^ (8*(p&7)))] = pk;
        }
        __syncthreads();
        f32x4 hacc[2][4];
        #pragma unroll
        for (int ot = 0; ot < 2; ++ot)
            #pragma unroll
            for (int pt = 0; pt < 4; ++pt)
                hacc[ot][pt] = (f32x4){bv[ot][0], bv[ot][1], bv[ot][2], bv[ot][3]};
        #pragma unroll
        for (int ks = 0; ks < 4; ++ks)
            #pragma unroll
            for (int pt = 0; pt < 4; ++pt) {
                short8 bfr = *(const short8*)&xT[(pt*16 + lm)*128 + ((ks*32 + 8*lg) ^ swzl)];
                hacc[0][pt] = __builtin_amdgcn_mfma_f32_16x16x32_bf16(af[0][ks], bfr, hacc[0][pt], 0,0,0);
                hacc[1][pt] = __builtin_amdgcn_mfma_f32_16x16x32_bf16(af[1][ks], bfr, hacc[1][pt], 0,0,0);
            }
        __syncthreads();
        #pragma unroll
        for (int ot = 0; ot < 2; ++ot)
            #pragma unroll
            for (int pt = 0; pt < 4; ++pt)
                #pragma unroll
                for (int r = 0; r < 4; ++r) {
                    float h = hacc[ot][pt][r];
                    s1[ot] += h; s2[ot] += h*h;
                }
    }
    #pragma unroll
    for (int ot = 0; ot < 2; ++ot) {
        float a = s1[ot], q = s2[ot];
        #pragma unroll
        for (int off = 1; off < 64; off <<= 1) {
            a += __shfl_xor(a, off); q += __shfl_xor(q, off);
        }
        if (l == 0) {
            int g = n*8 + 2*wid + ot;
            atomicAdd(&ws[WS_PART + g], a);
            atomicAdd(&ws[WS_PART + 80 + g], q);
        }
    }
}

__global__ void k2_fb(const float* __restrict__ b1, const float* __restrict__ gnw,
                      const float* __restrict__ gnb, float* ws) {
    __shared__ float muS[80], rsS[80];
    int t = threadIdx.x;
    if (t < 80) {
        const float inv = 1.0f/1048576.0f;
        float mu  = ws[WS_PART + t] * inv;
        float var = ws[WS_PART + 80 + t] * inv - mu*mu;
        muS[t] = mu;
        rsS[t] = rsqrtf(var + 1e-5f);
    }
    __syncthreads();
    for (int idx = t; idx < 1280; idx += 256) {
        int n = idx >> 7, o = idx & 127;
        int g = n*8 + (o >> 4);
        float a = rsS[g]*gnw[o];
        ws[WS_A  + idx] = a;
        ws[WS_CC + idx] = gnb[o] + (b1[o] - muS[g])*a;
    }
}

__global__ __launch_bounds__(512, 4) void k3_fb(const float* __restrict__ x,
        float* ws, const float* __restrict__ b2v, const float* __restrict__ temp,
        float* __restrict__ out) {
    __shared__ __align__(16) ushort xT[128*128];
    __shared__ __align__(16) ushort gT[128*128];
    const int t = threadIdx.x, b = blockIdx.x;
    const int n = b >> 9, strip = b & 511;
    const int h0 = (strip >> 4)*8, w0c = (strip & 15)*16;
    const int l = t & 63, wid = t >> 6;
    const int lm = l & 15, lg = l >> 4;
    const int swzl = 8*(lm&7);
    const ushort* w1b = (const ushort*)(ws + WS_W1BF);
    const ushort* w2b = (const ushort*)(ws + WS_W2BF);
    {
        const float* xb = x + (size_t)n*CH*HW + (size_t)h0*IMGW + w0c;
        const int q = lm & 3, dy = (lm >> 2) + 4*(wid >> 2);
        #pragma unroll
        for (int i = 0; i < 8; ++i) {
            int gc = (wid & 3)*8 + i;
            int c = 4*gc + lg;
            float4 v = *(const float4*)(xb + (size_t)c*HW + dy*IMGW + 4*q);
            float r0 = v.x, r1 = v.y, r2 = v.z, r3 = v.w;
            xpose4(lg, r0, r1, r2, r3);
            int col = 4*q + lg;
            int p = (col >> 3)*64 + dy*8 + (col & 7);
            uint2 pk; pk.x = pack2(r0, r1); pk.y = pack2(r2, r3);
            *(uint2*)&xT[p*128 + ((4*gc) ^ (8*(p&7)))] = pk;
        }
    }
    __syncthreads();
    const int win = wid >> 2, ow = wid & 3;
    const int o0 = 32*ow, pB = win*64;
    short8 af[2][4];
    #pragma unroll
    for (int ot = 0; ot < 2; ++ot)
        #pragma unroll
        for (int ks = 0; ks < 4; ++ks)
            af[ot][ks] = *(const short8*)(w1b + (size_t)(o0 + ot*16 + lm)*128 + ks*32 + 8*lg);
    f32x4 hacc[2][4];
    #pragma unroll
    for (int ot = 0; ot < 2; ++ot)
        #pragma unroll
        for (int pt = 0; pt < 4; ++pt) hacc[ot][pt] = (f32x4){0.f,0.f,0.f,0.f};
    #pragma unroll
    for (int ks = 0; ks < 4; ++ks)
        #pragma unroll
        for (int pt = 0; pt < 4; ++pt) {
            short8 bfr = *(const short8*)&xT[(pB + pt*16 + lm)*128 + ((ks*32 + 8*lg) ^ swzl)];
            hacc[0][pt] = __builtin_amdgcn_mfma_f32_16x16x32_bf16(af[0][ks], bfr, hacc[0][pt], 0,0,0);
            hacc[1][pt] = __builtin_amdgcn_mfma_f32_16x16x32_bf16(af[1][ks], bfr, hacc[1][pt], 0,0,0);
        }
    {
        const float* aP = ws + WS_A  + n*128;
        const float* cP = ws + WS_CC + n*128;
        #pragma unroll
        for (int ot = 0; ot < 2; ++ot) {
            float av[4], cv[4];
            #pragma unroll
            for (int r = 0; r < 4; ++r) {
                int o = o0 + ot*16 + 4*lg + r;
                av[r] = aP[o]; cv[r] = cP[o];
            }
            #pragma unroll
            for (int pt = 0; pt < 4; ++pt) {
                f32x4 h = hacc[ot][pt];
                float g0 = gelu_fast(fmaf(h[0], av[0], cv[0]));
                float g1 = gelu_fast(fmaf(h[1], av[1], cv[1]));
                float g2 = gelu_fast(fmaf(h[2], av[2], cv[2]));
                float g3 = gelu_fast(fmaf(h[3], av[3], cv[3]));
                int p = pB + pt*16 + lm;
                uint2 pk; pk.x = pack2(g0, g1); pk.y = pack2(g2, g3);
                *(uint2*)&gT[p*128 + ((o0 + ot*16 + 4*lg) ^ swzl)] = pk;
            }
        }
    }
    __syncthreads();
    short8 af2[2][4];
    #pragma unroll
    for (int ot = 0; ot < 2; ++ot)
        #pragma unroll
        for (int ks = 0; ks < 4; ++ks)
            af2[ot][ks] = *(const short8*)(w2b + (size_t)(o0 + ot*16 + lm)*128 + ks*32 + 8*lg);
    f32x4 facc[2][4];
    #pragma unroll
    for (int ot = 0; ot < 2; ++ot)
        #pragma unroll
        for (int pt = 0; pt < 4; ++pt) facc[ot][pt] = (f32x4){0.f,0.f,0.f,0.f};
    #pragma unroll
    for (int ks = 0; ks < 4; ++ks)
        #pragma unroll
        for (int pt = 0; pt < 4; ++pt) {
            short8 bfr = *(const short8*)&gT[(pB + pt*16 + lm)*128 + ((ks*32 + 8*lg) ^ swzl)];
            facc[0][pt] = __builtin_amdgcn_mfma_f32_16x16x32_bf16(af2[0][ks], bfr, facc[0][pt], 0,0,0);
            facc[1][pt] = __builtin_amdgcn_mfma_f32_16x16x32_bf16(af2[1][ks], bfr, facc[1][pt], 0,0,0);
        }
    {
        float b2r[2][4];
        #pragma unroll
        for (int ot = 0; ot < 2; ++ot)
            #pragma unroll
            for (int r = 0; r < 4; ++r) b2r[ot][r] = b2v[o0 + ot*16 + 4*lg + r];
        #pragma unroll
        for (int ot = 0; ot < 2; ++ot)
            #pragma unroll
            for (int pt = 0; pt < 4; ++pt) {
                f32x4 f = facc[ot][pt];
                float f0 = f[0] + b2r[ot][0], f1 = f[1] + b2r[ot][1];
                float f2 = f[2] + b2r[ot][2], f3 = f[3] + b2r[ot][3];
                int p = pt*16 + lm;
                int py = p >> 3, px = p & 7;
                float* ob = out + (size_t)n*CH*HW + (size_t)(o0 + ot*16 + 4*lg)*HW
                                + (size_t)(h0 + py)*IMGW + w0c + win*8 + px;
                ob[0] = f0; ob[HW] = f1; ob[2*HW] = f2; ob[3*HW] = f3;
                uint2 pk; pk.x = pack2(f0, f1); pk.y = pack2(f2, f3);
                *(uint2*)&xT[(pB + p)*128 + ((o0 + ot*16 + 4*lg) ^ swzl)] = pk;
            }
    }
    __syncthreads();
    const float invT = 1.f / temp[0];
    f32x4 sacc[4];
    #pragma unroll
    for (int qt = 0; qt < 4; ++qt) sacc[qt] = (f32x4){0.f,0.f,0.f,0.f};
    #pragma unroll
    for (int ks = 0; ks < 4; ++ks) {
        short8 afr = *(const short8*)&xT[(pB + 16*ow + lm)*128 + ((ks*32 + 8*lg) ^ swzl)];
        #pragma unroll
        for (int qt = 0; qt < 4; ++qt) {
            short8 bfr = *(const short8*)&xT[(pB + qt*16 + lm)*128 + ((ks*32 + 8*lg) ^ swzl)];
            sacc[qt] = __builtin_amdgcn_mfma_f32_16x16x32_bf16(afr, bfr, sacc[qt], 0,0,0);
        }
    }
    float lossAcc = 0.f;
    #pragma unroll
    for (int r = 0; r < 4; ++r) {
        float v0 = sacc[0][r]*invT, v1 = sacc[1][r]*invT;
        float v2 = sacc[2][r]*invT, v3 = sacc[3][r]*invT;
        float m = fmaxf(fmaxf(v0, v1), fmaxf(v2, v3));
        m = fmaxf(m, __shfl_xor(m, 1)); m = fmaxf(m, __shfl_xor(m, 2));
        m = fmaxf(m, __shfl_xor(m, 4)); m = fmaxf(m, __shfl_xor(m, 8));
        float s = __expf(v0-m) + __expf(v1-m) + __expf(v2-m) + __expf(v3-m);
        s += __shfl_xor(s, 1); s += __shfl_xor(s, 2);
        s += __shfl_xor(s, 4); s += __shfl_xor(s, 8);
        float lse = m + logf(s);
        if (lm == 4*lg + r) {
            float dv = (ow == 0) ? v0 : (ow == 1) ? v1 : (ow == 2) ? v2 : v3;
            lossAcc += lse - dv;
        }
    }
    lossAcc += __shfl_xor(lossAcc, 1);  lossAcc += __shfl_xor(lossAcc, 2);
    lossAcc += __shfl_xor(lossAcc, 4);  lossAcc += __shfl_xor(lossAcc, 8);
    lossAcc += __shfl_xor(lossAcc, 16); lossAcc += __shfl_xor(lossAcc, 32);
    if (l == 0) ws[WS_LOSS + (size_t)b*8 + wid] = lossAcc;
}

// ------------------------------------------ K4: deterministic loss reduction
__global__ void k4_loss(const float* __restrict__ ws, float* __restrict__ out) {
    __shared__ float red[4];
    int t = threadIdx.x;
    float s = 0.f;
    for (int i = t; i < 40960; i += 256) s += ws[WS_LOSS + i];
    #pragma unroll
    for (int off = 32; off > 0; off >>= 1) s += __shfl_down(s, off, 64);
    if ((t & 63) == 0) red[t >> 6] = s;
    __syncthreads();
    if (t == 0) out[FEATS_ELEMS] = (red[0] + red[1] + red[2] + red[3]) * (1.f/655360.f);
}

// ---------------------------------------------------------------- launcher
extern "C" void kernel_launch(void* const* d_in, const int* in_sizes, int n_in,
                              void* d_out, int out_size, void* d_ws, size_t ws_size,
                              hipStream_t stream) {
    (void)in_sizes; (void)n_in; (void)out_size;
    const float* x    = (const float*)d_in[0];
    const float* W1   = (const float*)d_in[1];
    const float* b1   = (const float*)d_in[2];
    const float* gnw  = (const float*)d_in[3];
    const float* gnb  = (const float*)d_in[4];
    const float* W2   = (const float*)d_in[5];
    const float* b2   = (const float*)d_in[6];
    const float* temp = (const float*)d_in[7];
    float* out = (float*)d_out;
    float* ws  = (float*)d_ws;

    hipLaunchKernelGGL(k0_init, dim3(64), dim3(256), 0, stream, W1, W2, ws);
    if (ws_size >= (size_t)NEED_FLOATS * sizeof(float)) {
        hipLaunchKernelGGL(k1_cache,   dim3(5120), dim3(512), 0, stream, x, ws, b1);
        hipLaunchKernelGGL(k2_cache,   dim3(1),    dim3(256), 0, stream, gnw, gnb, ws);
        hipLaunchKernelGGL(k3_consume, dim3(5120), dim3(512), 0, stream, ws, b2, temp, out);
    } else {
        hipLaunchKernelGGL(k1_fb, dim3(640),  dim3(256), 0, stream, x, ws, b1);
        hipLaunchKernelGGL(k2_fb, dim3(1),    dim3(256), 0, stream, b1, gnw, gnb, ws);
        hipLaunchKernelGGL(k3_fb, dim3(5120), dim3(512), 0, stream, x, ws, b2, temp, out);
    }
    hipLaunchKernelGGL(k4_loss, dim3(1), dim3(256), 0, stream, ws, out);
}

// Round 5
// 434.481 us; speedup vs baseline: 3.4295x; 1.0457x over previous
//
#include <hip/hip_runtime.h>
#include <hip/hip_bf16.h>
#include <math.h>

#define CH 128
#define IMGW 256
#define NIMG 10
#define HW 65536
#define FEATS_ELEMS ((size_t)NIMG*CH*HW)

typedef __attribute__((ext_vector_type(8))) short short8;
typedef __attribute__((ext_vector_type(4))) float f32x4;

// workspace layout (float offsets)
#define WS_W1BF 0          // W1 bf16 [128 o][128 c]
#define WS_W2BF 8192
#define WS_PART 16384      // [5120 swz-strips][16] block stat partials
#define WS_A    98304      // [10][128] rsig*gn_w
#define WS_CC   99584      // [10][128] affine constant
#define WS_LOSS 100864     // [10240*4] per-(window,wave) loss partials
#define WS_HT   141824     // h cache: 5120 strips * 8192 floats (16384 bf16)

static __device__ __forceinline__ ushort f2bf(float f) {
    __hip_bfloat16 h = __float2bfloat16(f);
    return *reinterpret_cast<ushort*>(&h);
}
static __device__ __forceinline__ uint pack2(float a, float b) {
    return (uint)f2bf(a) | ((uint)f2bf(b) << 16);
}
static __device__ __forceinline__ float gelu_fast(float v) {
    float v2 = v*v;
    float z2 = v * fmaf(0.07135481627f, v2, 1.59576912161f);
    return v / (1.0f + __expf(-z2));
}
// 4x4 cross-lane transpose among lanes {l, l^16, l^32, l^48}
static __device__ __forceinline__ void xpose4(int lg, float& r0, float& r1,
                                              float& r2, float& r3) {
    float s0v = (lg&2) ? r0 : r2, s1v = (lg&2) ? r1 : r3;
    float u0 = __shfl_xor(s0v, 32), u1 = __shfl_xor(s1v, 32);
    if (lg&2) { r0 = u0; r1 = u1; } else { r2 = u0; r3 = u1; }
    float sA = (lg&1) ? r0 : r1; float uA = __shfl_xor(sA, 16);
    if (lg&1) r0 = uA; else r1 = uA;
    float sB = (lg&1) ? r2 : r3; float uB = __shfl_xor(sB, 16);
    if (lg&1) r2 = uB; else r3 = uB;
}

// ------------------------------------------------ K0: W->bf16
__global__ void k0_init(const float* __restrict__ W1, const float* __restrict__ W2,
                        float* __restrict__ ws) {
    int idx = blockIdx.x*256 + threadIdx.x;     // 0..16383
    uint* w1b = (uint*)(ws + WS_W1BF);
    uint* w2b = (uint*)(ws + WS_W2BF);
    if (idx < 8192) {
        w1b[idx] = pack2(W1[2*idx], W1[2*idx+1]);
    } else {
        int j = idx - 8192;
        w2b[j] = pack2(W2[2*j], W2[2*j+1]);
    }
}

// K1: stage x strip -> conv1(+b1) -> stats partials -> store h^T (bf16, swizzled)
// XCD-chunked swizzle: strips s and s+1 (sharing HBM lines) stay on one XCD.
__global__ __launch_bounds__(512, 8) void k1_cache(const float* __restrict__ x,
        float* ws, const float* __restrict__ b1v) {
    __shared__ __align__(16) ushort xT[128*128];   // x^T then h^T  (32 KB)
    __shared__ float sp[32];
    const int t = threadIdx.x, b = blockIdx.x;
    const int swz = (b & 7)*640 + (b >> 3);        // bijective, 5120%8==0
    const int n = swz >> 9, strip = swz & 511;
    const int h0 = (strip >> 4)*8, w0c = (strip & 15)*16;
    const int l = t & 63, wid = t >> 6;
    const int lm = l & 15, lg = l >> 4;
    const int swzl = 8*(lm&7);
    const ushort* w1b = (const ushort*)(ws + WS_W1BF);

    // ---- stage strip: fp32 -> 4x4 shfl transpose -> bf16 xT[p][c^swz]
    {
        const float* xb = x + (size_t)n*CH*HW + (size_t)h0*IMGW + w0c;
        const int q = lm & 3, dy = (lm >> 2) + 4*(wid >> 2);
        #pragma unroll
        for (int i = 0; i < 8; ++i) {
            int gc = (wid & 3)*8 + i;
            int c = 4*gc + lg;
            float4 v = *(const float4*)(xb + (size_t)c*HW + dy*IMGW + 4*q);
            float r0 = v.x, r1 = v.y, r2 = v.z, r3 = v.w;
            xpose4(lg, r0, r1, r2, r3);
            int col = 4*q + lg;
            int p = (col >> 3)*64 + dy*8 + (col & 7);
            uint2 pk; pk.x = pack2(r0, r1); pk.y = pack2(r2, r3);
            *(uint2*)&xT[p*128 + ((4*gc) ^ (8*(p&7)))] = pk;
        }
    }
    __syncthreads();

    const int win = wid >> 2, ow = wid & 3;
    const int o0 = 32*ow, pB = win*64;

    // ---- conv1 (h includes b1)
    short8 af[2][4];
    #pragma unroll
    for (int ot = 0; ot < 2; ++ot)
        #pragma unroll
        for (int ks = 0; ks < 4; ++ks)
            af[ot][ks] = *(const short8*)(w1b + (size_t)(o0 + ot*16 + lm)*128 + ks*32 + 8*lg);
    f32x4 hacc[2][4];
    #pragma unroll
    for (int ot = 0; ot < 2; ++ot) {
        float b0 = b1v[o0 + ot*16 + 4*lg + 0], c1 = b1v[o0 + ot*16 + 4*lg + 1];
        float c2 = b1v[o0 + ot*16 + 4*lg + 2], c3 = b1v[o0 + ot*16 + 4*lg + 3];
        #pragma unroll
        for (int pt = 0; pt < 4; ++pt) hacc[ot][pt] = (f32x4){b0, c1, c2, c3};
    }
    #pragma unroll
    for (int ks = 0; ks < 4; ++ks)
        #pragma unroll
        for (int pt = 0; pt < 4; ++pt) {
            short8 bfr = *(const short8*)&xT[(pB + pt*16 + lm)*128 + ((ks*32 + 8*lg) ^ swzl)];
            hacc[0][pt] = __builtin_amdgcn_mfma_f32_16x16x32_bf16(af[0][ks], bfr, hacc[0][pt], 0,0,0);
            hacc[1][pt] = __builtin_amdgcn_mfma_f32_16x16x32_bf16(af[1][ks], bfr, hacc[1][pt], 0,0,0);
        }

    // ---- stats: per-wave group sums -> sp
    float s1[2] = {0.f, 0.f}, s2[2] = {0.f, 0.f};
    #pragma unroll
    for (int ot = 0; ot < 2; ++ot)
        #pragma unroll
        for (int pt = 0; pt < 4; ++pt)
            #pragma unroll
            for (int r = 0; r < 4; ++r) {
                float h = hacc[ot][pt][r];
                s1[ot] += h; s2[ot] += h*h;
            }
    #pragma unroll
    for (int ot = 0; ot < 2; ++ot) {
        float a = s1[ot], q = s2[ot];
        #pragma unroll
        for (int off = 1; off < 64; off <<= 1) {
            a += __shfl_xor(a, off); q += __shfl_xor(q, off);
        }
        if (l == 0) { sp[wid*4 + ot*2] = a; sp[wid*4 + ot*2 + 1] = q; }
    }
    __syncthreads();   // sp ready; also: all conv1 xT reads complete

    if (t < 16) {
        int g = t & 7, which = t >> 3;
        int w0 = g >> 1, slot = (g & 1)*2 + which;
        float v = sp[w0*4 + slot] + sp[(4 + w0)*4 + slot];
        ws[WS_PART + (size_t)swz*16 + which*8 + g] = v;   // indexed by swz => grouped by n
    }

    // ---- h^T write in-place into xT: [p][o^swz]
    #pragma unroll
    for (int ot = 0; ot < 2; ++ot)
        #pragma unroll
        for (int pt = 0; pt < 4; ++pt) {
            f32x4 h = hacc[ot][pt];
            int p = pB + pt*16 + lm;
            uint2 pk; pk.x = pack2(h[0], h[1]); pk.y = pack2(h[2], h[3]);
            *(uint2*)&xT[p*128 + ((o0 + ot*16 + 4*lg) ^ swzl)] = pk;
        }
    __syncthreads();

    // ---- stream LDS -> global h cache (verbatim, coalesced; window-contiguous)
    const uint4* srcv = (const uint4*)xT;
    uint4* dstv = (uint4*)(ws + WS_HT + (size_t)swz*8192);
    #pragma unroll
    for (int i = 0; i < 4; ++i) dstv[t + i*512] = srcv[t + i*512];
}

// K2: parallel reduce of block partials (grid 10 = one block per image)
__global__ __launch_bounds__(256) void k2_final(const float* __restrict__ gnw,
        const float* __restrict__ gnb, float* ws) {
    __shared__ float red[256];
    __shared__ float tot[16];
    __shared__ float muS[8], rsS[8];
    const int t = threadIdx.x, n = blockIdx.x;
    const int s = t & 15, i0 = t >> 4;
    const float* base = ws + WS_PART + (size_t)n*512*16;
    float p = 0.f;
    for (int k = 0; k < 32; ++k) p += base[(i0 + 16*k)*16 + s];   // coalesced 1KB/iter
    red[t] = p;
    __syncthreads();
    if (t < 16) {
        float v = 0.f;
        #pragma unroll
        for (int j = 0; j < 16; ++j) v += red[j*16 + t];
        tot[t] = v;
    }
    __syncthreads();
    if (t < 8) {
        const float inv = 1.0f/1048576.0f;      // 16 ch * 65536 px
        float mu  = tot[t]*inv;
        float var = tot[8 + t]*inv - mu*mu;
        muS[t] = mu; rsS[t] = rsqrtf(var + 1e-5f);
    }
    __syncthreads();
    if (t < 128) {
        int g = t >> 4;
        float a = rsS[g]*gnw[t];
        ws[WS_A  + n*128 + t] = a;
        ws[WS_CC + n*128 + t] = gnb[t] - muS[g]*a;   // b1 already inside h
    }
}

// K3: one block per 8x8 window (256 thr, 16 KB LDS, up to 8 blocks/CU).
// load h chunk -> GN+GELU in place -> conv2 -> feats + Gram + LSE.
__global__ __launch_bounds__(256, 8) void k3_win(float* ws,
        const float* __restrict__ b2v, const float* __restrict__ temp,
        float* __restrict__ out) {
    __shared__ __align__(16) ushort fb[64*128];    // h -> g -> f  (16 KB)
    const int t = threadIdx.x, b = blockIdx.x;
    const int swz = (b & 7)*1280 + (b >> 3);       // bijective, 10240%8==0
    const int n = swz >> 10, widx = swz & 1023;
    const int h0 = (widx >> 5)*8, w0 = (widx & 31)*8;
    const int l = t & 63, ow = t >> 6;             // 4 waves = 4 o-quarters
    const int lm = l & 15, lg = l >> 4;
    const int swzl = 8*(lm&7);
    const ushort* w2b = (const ushort*)(ws + WS_W2BF);

    // ---- load h window chunk (verbatim 16 KB; strip = swz>>1, half = widx&1)
    {
        const uint4* srcv = (const uint4*)(ws + WS_HT + (size_t)(swz >> 1)*8192
                                           + (size_t)(widx & 1)*4096);
        uint4* dstv = (uint4*)fb;
        #pragma unroll
        for (int i = 0; i < 4; ++i) dstv[t + i*256] = srcv[t + i*256];
    }
    __syncthreads();

    // ---- GN affine + GELU, in place (2048 uint2 / 256 thr)
    {
        uint2* hu = (uint2*)fb;
        const float* aP = ws + WS_A  + n*128;
        const float* cP = ws + WS_CC + n*128;
        #pragma unroll
        for (int i = 0; i < 8; ++i) {
            int c0 = t + i*256;
            int p = c0 >> 5;
            int o = ((c0 & 31)*4) ^ (8*(p&7));
            uint2 v = hu[c0];
            float hv0 = __uint_as_float((v.x & 0xffffu) << 16);
            float hv1 = __uint_as_float(v.x & 0xffff0000u);
            float hv2 = __uint_as_float((v.y & 0xffffu) << 16);
            float hv3 = __uint_as_float(v.y & 0xffff0000u);
            float g0 = gelu_fast(fmaf(hv0, aP[o],   cP[o]));
            float g1 = gelu_fast(fmaf(hv1, aP[o+1], cP[o+1]));
            float g2 = gelu_fast(fmaf(hv2, aP[o+2], cP[o+2]));
            float g3 = gelu_fast(fmaf(hv3, aP[o+3], cP[o+3]));
            uint2 pk; pk.x = pack2(g0, g1); pk.y = pack2(g2, g3);
            hu[c0] = pk;
        }
    }
    __syncthreads();

    const int o0 = 32*ow;

    // ---- conv2
    short8 af2[2][4];
    #pragma unroll
    for (int ot = 0; ot < 2; ++ot)
        #pragma unroll
        for (int ks = 0; ks < 4; ++ks)
            af2[ot][ks] = *(const short8*)(w2b + (size_t)(o0 + ot*16 + lm)*128 + ks*32 + 8*lg);
    f32x4 facc[2][4];
    #pragma unroll
    for (int ot = 0; ot < 2; ++ot)
        #pragma unroll
        for (int pt = 0; pt < 4; ++pt) facc[ot][pt] = (f32x4){0.f,0.f,0.f,0.f};
    #pragma unroll
    for (int ks = 0; ks < 4; ++ks)
        #pragma unroll
        for (int pt = 0; pt < 4; ++pt) {
            short8 bfr = *(const short8*)&fb[(pt*16 + lm)*128 + ((ks*32 + 8*lg) ^ swzl)];
            facc[0][pt] = __builtin_amdgcn_mfma_f32_16x16x32_bf16(af2[0][ks], bfr, facc[0][pt], 0,0,0);
            facc[1][pt] = __builtin_amdgcn_mfma_f32_16x16x32_bf16(af2[1][ks], bfr, facc[1][pt], 0,0,0);
        }
    __syncthreads();   // all g reads done before f overwrites

    // ---- feats store (fp32) + f^T (bf16) in place
    {
        float b2r[2][4];
        #pragma unroll
        for (int ot = 0; ot < 2; ++ot)
            #pragma unroll
            for (int r = 0; r < 4; ++r) b2r[ot][r] = b2v[o0 + ot*16 + 4*lg + r];
        #pragma unroll
        for (int ot = 0; ot < 2; ++ot)
            #pragma unroll
            for (int pt = 0; pt < 4; ++pt) {
                f32x4 f = facc[ot][pt];
                float f0 = f[0] + b2r[ot][0], f1 = f[1] + b2r[ot][1];
                float f2 = f[2] + b2r[ot][2], f3 = f[3] + b2r[ot][3];
                int p = pt*16 + lm;
                int py = p >> 3, px = p & 7;
                float* ob = out + (size_t)n*CH*HW + (size_t)(o0 + ot*16 + 4*lg)*HW
                                + (size_t)(h0 + py)*IMGW + w0 + px;
                ob[0] = f0; ob[HW] = f1; ob[2*HW] = f2; ob[3*HW] = f3;
                uint2 pk; pk.x = pack2(f0, f1); pk.y = pack2(f2, f3);
                *(uint2*)&fb[p*128 + ((o0 + ot*16 + 4*lg) ^ swzl)] = pk;
            }
    }
    __syncthreads();

    // ---- Gram (rows [16*ow,16*ow+16) x all 64 q) + row LSE + loss partial
    const float invT = 1.f / temp[0];
    f32x4 sacc[4];
    #pragma unroll
    for (int qt = 0; qt < 4; ++qt) sacc[qt] = (f32x4){0.f,0.f,0.f,0.f};
    #pragma unroll
    for (int ks = 0; ks < 4; ++ks) {
        short8 afr = *(const short8*)&fb[(16*ow + lm)*128 + ((ks*32 + 8*lg) ^ swzl)];
        #pragma unroll
        for (int qt = 0; qt < 4; ++qt) {
            short8 bfr = *(const short8*)&fb[(qt*16 + lm)*128 + ((ks*32 + 8*lg) ^ swzl)];
            sacc[qt] = __builtin_amdgcn_mfma_f32_16x16x32_bf16(afr, bfr, sacc[qt], 0,0,0);
        }
    }
    float lossAcc = 0.f;
    #pragma unroll
    for (int r = 0; r < 4; ++r) {
        float v0 = sacc[0][r]*invT, v1 = sacc[1][r]*invT;
        float v2 = sacc[2][r]*invT, v3 = sacc[3][r]*invT;
        float m = fmaxf(fmaxf(v0, v1), fmaxf(v2, v3));
        m = fmaxf(m, __shfl_xor(m, 1)); m = fmaxf(m, __shfl_xor(m, 2));
        m = fmaxf(m, __shfl_xor(m, 4)); m = fmaxf(m, __shfl_xor(m, 8));
        float s = __expf(v0-m) + __expf(v1-m) + __expf(v2-m) + __expf(v3-m);
        s += __shfl_xor(s, 1); s += __shfl_xor(s, 2);
        s += __shfl_xor(s, 4); s += __shfl_xor(s, 8);
        float lse = m + logf(s);
        if (lm == 4*lg + r) {
            float dv = (ow == 0) ? v0 : (ow == 1) ? v1 : (ow == 2) ? v2 : v3;
            lossAcc += lse - dv;
        }
    }
    lossAcc += __shfl_xor(lossAcc, 1);  lossAcc += __shfl_xor(lossAcc, 2);
    lossAcc += __shfl_xor(lossAcc, 4);  lossAcc += __shfl_xor(lossAcc, 8);
    lossAcc += __shfl_xor(lossAcc, 16); lossAcc += __shfl_xor(lossAcc, 32);
    if (l == 0) ws[WS_LOSS + (size_t)b*4 + ow] = lossAcc;
}

// ------------------------------------------ K4: deterministic loss reduction
__global__ void k4_loss(const float* __restrict__ ws, float* __restrict__ out) {
    __shared__ float red[4];
    int t = threadIdx.x;
    float s = 0.f;
    for (int i = t; i < 40960; i += 256) s += ws[WS_LOSS + i];
    #pragma unroll
    for (int off = 32; off > 0; off >>= 1) s += __shfl_down(s, off, 64);
    if ((t & 63) == 0) red[t >> 6] = s;
    __syncthreads();
    if (t == 0) out[FEATS_ELEMS] = (red[0] + red[1] + red[2] + red[3]) * (1.f/655360.f);
}

// ---------------------------------------------------------------- launcher
extern "C" void kernel_launch(void* const* d_in, const int* in_sizes, int n_in,
                              void* d_out, int out_size, void* d_ws, size_t ws_size,
                              hipStream_t stream) {
    (void)in_sizes; (void)n_in; (void)out_size; (void)ws_size;
    const float* x    = (const float*)d_in[0];
    const float* W1   = (const float*)d_in[1];
    const float* b1   = (const float*)d_in[2];
    const float* gnw  = (const float*)d_in[3];
    const float* gnb  = (const float*)d_in[4];
    const float* W2   = (const float*)d_in[5];
    const float* b2   = (const float*)d_in[6];
    const float* temp = (const float*)d_in[7];
    float* out = (float*)d_out;
    float* ws  = (float*)d_ws;

    hipLaunchKernelGGL(k0_init,  dim3(64),    dim3(256), 0, stream, W1, W2, ws);
    hipLaunchKernelGGL(k1_cache, dim3(5120),  dim3(512), 0, stream, x, ws, b1);
    hipLaunchKernelGGL(k2_final, dim3(10),    dim3(256), 0, stream, gnw, gnb, ws);
    hipLaunchKernelGGL(k3_win,   dim3(10240), dim3(256), 0, stream, ws, b2, temp, out);
    hipLaunchKernelGGL(k4_loss,  dim3(1),     dim3(256), 0, stream, ws, out);
}

// Round 6
// 395.315 us; speedup vs baseline: 3.7693x; 1.0991x over previous
//
#include <hip/hip_runtime.h>
#include <hip/hip_bf16.h>
#include <math.h>

#define CH 128
#define IMGW 256
#define NIMG 10
#define HW 65536
#define FEATS_ELEMS ((size_t)NIMG*CH*HW)

typedef __attribute__((ext_vector_type(8))) short short8;
typedef __attribute__((ext_vector_type(4))) float f32x4;
typedef __attribute__((ext_vector_type(4))) unsigned int u32x4;

// workspace layout (float offsets)
#define WS_W1BF 0          // W1 bf16 [128 o][128 c]
#define WS_W2BF 8192
#define WS_PART 16384      // [5120 swz-strips][16] block stat partials
#define WS_A    98304      // [10][128] rsig*gn_w
#define WS_CC   99584      // [10][128] affine constant
#define WS_LOSS 100864     // [5120*8] per-(strip,wave) loss partials
#define WS_HT   141824     // h cache: 5120 strips * 8192 floats (16384 bf16)

static __device__ __forceinline__ ushort f2bf(float f) {
    __hip_bfloat16 h = __float2bfloat16(f);
    return *reinterpret_cast<ushort*>(&h);
}
static __device__ __forceinline__ uint pack2(float a, float b) {
    return (uint)f2bf(a) | ((uint)f2bf(b) << 16);
}
static __device__ __forceinline__ float gelu_fast(float v) {
    float v2 = v*v;
    float z2 = v * fmaf(0.07135481627f, v2, 1.59576912161f);
    return v / (1.0f + __expf(-z2));
}
// 4x4 cross-lane transpose among lanes {l, l^16, l^32, l^48}
static __device__ __forceinline__ void xpose4(int lg, float& r0, float& r1,
                                              float& r2, float& r3) {
    float s0v = (lg&2) ? r0 : r2, s1v = (lg&2) ? r1 : r3;
    float u0 = __shfl_xor(s0v, 32), u1 = __shfl_xor(s1v, 32);
    if (lg&2) { r0 = u0; r1 = u1; } else { r2 = u0; r3 = u1; }
    float sA = (lg&1) ? r0 : r1; float uA = __shfl_xor(sA, 16);
    if (lg&1) r0 = uA; else r1 = uA;
    float sB = (lg&1) ? r2 : r3; float uB = __shfl_xor(sB, 16);
    if (lg&1) r2 = uB; else r3 = uB;
}

// ------------------------------------------------ K0: W->bf16
__global__ void k0_init(const float* __restrict__ W1, const float* __restrict__ W2,
                        float* __restrict__ ws) {
    int idx = blockIdx.x*256 + threadIdx.x;     // 0..16383
    uint* w1b = (uint*)(ws + WS_W1BF);
    uint* w2b = (uint*)(ws + WS_W2BF);
    if (idx < 8192) {
        w1b[idx] = pack2(W1[2*idx], W1[2*idx+1]);
    } else {
        int j = idx - 8192;
        w2b[j] = pack2(W2[2*j], W2[2*j+1]);
    }
}

// K1: stage x strip -> conv1(+b1) -> stats partials -> store h^T (bf16, swizzled)
// NT x-loads (read-once; keep L2/L3 for the h cache). All 8 loads hoisted
// ahead of the shfl-transpose chain for 8 outstanding HBM requests/thread.
__global__ __launch_bounds__(512, 8) void k1_cache(const float* __restrict__ x,
        float* ws, const float* __restrict__ b1v) {
    __shared__ __align__(16) ushort xT[128*128];   // x^T then h^T  (32 KB)
    __shared__ float sp[32];
    const int t = threadIdx.x, b = blockIdx.x;
    const int swz = (b & 7)*640 + (b >> 3);        // bijective, 5120%8==0
    const int n = swz >> 9, strip = swz & 511;
    const int h0 = (strip >> 4)*8, w0c = (strip & 15)*16;
    const int l = t & 63, wid = t >> 6;
    const int lm = l & 15, lg = l >> 4;
    const int swzl = 8*(lm&7);
    const ushort* w1b = (const ushort*)(ws + WS_W1BF);

    // ---- stage strip: all loads first (NT), then transpose+pack to LDS
    {
        const float* xb = x + (size_t)n*CH*HW + (size_t)h0*IMGW + w0c;
        const int q = lm & 3, dy = (lm >> 2) + 4*(wid >> 2);
        f32x4 v[8];
        #pragma unroll
        for (int i = 0; i < 8; ++i) {
            int gc = (wid & 3)*8 + i;
            int c = 4*gc + lg;
            v[i] = __builtin_nontemporal_load(
                       (const f32x4*)(xb + (size_t)c*HW + dy*IMGW + 4*q));
        }
        #pragma unroll
        for (int i = 0; i < 8; ++i) {
            int gc = (wid & 3)*8 + i;
            float r0 = v[i][0], r1 = v[i][1], r2 = v[i][2], r3 = v[i][3];
            xpose4(lg, r0, r1, r2, r3);
            int col = 4*q + lg;
            int p = (col >> 3)*64 + dy*8 + (col & 7);
            uint2 pk; pk.x = pack2(r0, r1); pk.y = pack2(r2, r3);
            *(uint2*)&xT[p*128 + ((4*gc) ^ (8*(p&7)))] = pk;
        }
    }
    __syncthreads();

    const int win = wid >> 2, ow = wid & 3;
    const int o0 = 32*ow, pB = win*64;

    // ---- conv1 (h includes b1)
    short8 af[2][4];
    #pragma unroll
    for (int ot = 0; ot < 2; ++ot)
        #pragma unroll
        for (int ks = 0; ks < 4; ++ks)
            af[ot][ks] = *(const short8*)(w1b + (size_t)(o0 + ot*16 + lm)*128 + ks*32 + 8*lg);
    f32x4 hacc[2][4];
    #pragma unroll
    for (int ot = 0; ot < 2; ++ot) {
        float b0 = b1v[o0 + ot*16 + 4*lg + 0], c1 = b1v[o0 + ot*16 + 4*lg + 1];
        float c2 = b1v[o0 + ot*16 + 4*lg + 2], c3 = b1v[o0 + ot*16 + 4*lg + 3];
        #pragma unroll
        for (int pt = 0; pt < 4; ++pt) hacc[ot][pt] = (f32x4){b0, c1, c2, c3};
    }
    #pragma unroll
    for (int ks = 0; ks < 4; ++ks)
        #pragma unroll
        for (int pt = 0; pt < 4; ++pt) {
            short8 bfr = *(const short8*)&xT[(pB + pt*16 + lm)*128 + ((ks*32 + 8*lg) ^ swzl)];
            hacc[0][pt] = __builtin_amdgcn_mfma_f32_16x16x32_bf16(af[0][ks], bfr, hacc[0][pt], 0,0,0);
            hacc[1][pt] = __builtin_amdgcn_mfma_f32_16x16x32_bf16(af[1][ks], bfr, hacc[1][pt], 0,0,0);
        }

    // ---- stats: per-wave group sums -> sp
    float s1[2] = {0.f, 0.f}, s2[2] = {0.f, 0.f};
    #pragma unroll
    for (int ot = 0; ot < 2; ++ot)
        #pragma unroll
        for (int pt = 0; pt < 4; ++pt)
            #pragma unroll
            for (int r = 0; r < 4; ++r) {
                float h = hacc[ot][pt][r];
                s1[ot] += h; s2[ot] += h*h;
            }
    #pragma unroll
    for (int ot = 0; ot < 2; ++ot) {
        float a = s1[ot], q = s2[ot];
        #pragma unroll
        for (int off = 1; off < 64; off <<= 1) {
            a += __shfl_xor(a, off); q += __shfl_xor(q, off);
        }
        if (l == 0) { sp[wid*4 + ot*2] = a; sp[wid*4 + ot*2 + 1] = q; }
    }
    __syncthreads();   // sp ready; also: all conv1 xT reads complete

    if (t < 16) {
        int g = t & 7, which = t >> 3;
        int w0 = g >> 1, slot = (g & 1)*2 + which;
        float v = sp[w0*4 + slot] + sp[(4 + w0)*4 + slot];
        ws[WS_PART + (size_t)swz*16 + which*8 + g] = v;   // grouped by n
    }

    // ---- h^T write in-place into xT: [p][o^swz]
    #pragma unroll
    for (int ot = 0; ot < 2; ++ot)
        #pragma unroll
        for (int pt = 0; pt < 4; ++pt) {
            f32x4 h = hacc[ot][pt];
            int p = pB + pt*16 + lm;
            uint2 pk; pk.x = pack2(h[0], h[1]); pk.y = pack2(h[2], h[3]);
            *(uint2*)&xT[p*128 + ((o0 + ot*16 + 4*lg) ^ swzl)] = pk;
        }
    __syncthreads();

    // ---- stream LDS -> global h cache (plain stores: want L2/L3 residency)
    const uint4* srcv = (const uint4*)xT;
    uint4* dstv = (uint4*)(ws + WS_HT + (size_t)swz*8192);
    #pragma unroll
    for (int i = 0; i < 4; ++i) dstv[t + i*512] = srcv[t + i*512];
}

// K2: parallel reduce of block partials (grid 10 = one block per image)
__global__ __launch_bounds__(256) void k2_final(const float* __restrict__ gnw,
        const float* __restrict__ gnb, float* ws) {
    __shared__ float red[256];
    __shared__ float tot[16];
    __shared__ float muS[8], rsS[8];
    const int t = threadIdx.x, n = blockIdx.x;
    const int s = t & 15, i0 = t >> 4;
    const float* base = ws + WS_PART + (size_t)n*512*16;
    float p = 0.f;
    for (int k = 0; k < 32; ++k) p += base[(i0 + 16*k)*16 + s];
    red[t] = p;
    __syncthreads();
    if (t < 16) {
        float v = 0.f;
        #pragma unroll
        for (int j = 0; j < 16; ++j) v += red[j*16 + t];
        tot[t] = v;
    }
    __syncthreads();
    if (t < 8) {
        const float inv = 1.0f/1048576.0f;      // 16 ch * 65536 px
        float mu  = tot[t]*inv;
        float var = tot[8 + t]*inv - mu*mu;
        muS[t] = mu; rsS[t] = rsqrtf(var + 1e-5f);
    }
    __syncthreads();
    if (t < 128) {
        int g = t >> 4;
        float a = rsS[g]*gnw[t];
        ws[WS_A  + n*128 + t] = a;
        ws[WS_CC + n*128 + t] = gnb[t] - muS[g]*a;   // b1 already inside h
    }
}

// K3: 2-window strip (512 thr, 32 KB LDS), XCD-chunked swizzle matching k1.
// load h strip (NT) -> GN+GELU in place -> conv2 -> feats + Gram + LSE.
__global__ __launch_bounds__(512, 8) void k3_consume(float* ws,
        const float* __restrict__ b2v, const float* __restrict__ temp,
        float* __restrict__ out) {
    __shared__ __align__(16) ushort fb[128*128];   // h -> g -> f  (32 KB)
    const int t = threadIdx.x, b = blockIdx.x;
    const int swz = (b & 7)*640 + (b >> 3);        // same bijection as k1
    const int n = swz >> 9, strip = swz & 511;
    const int h0 = (strip >> 4)*8, w0c = (strip & 15)*16;
    const int l = t & 63, wid = t >> 6;
    const int lm = l & 15, lg = l >> 4;
    const int swzl = 8*(lm&7);
    const ushort* w2b = (const ushort*)(ws + WS_W2BF);

    // ---- load h strip (verbatim, NT: read-once)
    {
        const u32x4* srcv = (const u32x4*)(ws + WS_HT + (size_t)swz*8192);
        u32x4* dstv = (u32x4*)fb;
        #pragma unroll
        for (int i = 0; i < 4; ++i)
            dstv[t + i*512] = __builtin_nontemporal_load(srcv + t + i*512);
    }
    __syncthreads();

    // ---- GN affine + GELU, in place (4096 uint2 / 512 thr)
    {
        uint2* hu = (uint2*)fb;
        const float* aP = ws + WS_A  + n*128;
        const float* cP = ws + WS_CC + n*128;
        #pragma unroll
        for (int i = 0; i < 8; ++i) {
            int c0 = t + i*512;
            int p = c0 >> 5;
            int o = ((c0 & 31)*4) ^ (8*(p&7));
            uint2 v = hu[c0];
            float hv0 = __uint_as_float((v.x & 0xffffu) << 16);
            float hv1 = __uint_as_float(v.x & 0xffff0000u);
            float hv2 = __uint_as_float((v.y & 0xffffu) << 16);
            float hv3 = __uint_as_float(v.y & 0xffff0000u);
            float g0 = gelu_fast(fmaf(hv0, aP[o],   cP[o]));
            float g1 = gelu_fast(fmaf(hv1, aP[o+1], cP[o+1]));
            float g2 = gelu_fast(fmaf(hv2, aP[o+2], cP[o+2]));
            float g3 = gelu_fast(fmaf(hv3, aP[o+3], cP[o+3]));
            uint2 pk; pk.x = pack2(g0, g1); pk.y = pack2(g2, g3);
            hu[c0] = pk;
        }
    }
    __syncthreads();

    const int win = wid >> 2, ow = wid & 3;
    const int o0 = 32*ow, pB = win*64;

    // ---- conv2
    short8 af2[2][4];
    #pragma unroll
    for (int ot = 0; ot < 2; ++ot)
        #pragma unroll
        for (int ks = 0; ks < 4; ++ks)
            af2[ot][ks] = *(const short8*)(w2b + (size_t)(o0 + ot*16 + lm)*128 + ks*32 + 8*lg);
    f32x4 facc[2][4];
    #pragma unroll
    for (int ot = 0; ot < 2; ++ot)
        #pragma unroll
        for (int pt = 0; pt < 4; ++pt) facc[ot][pt] = (f32x4){0.f,0.f,0.f,0.f};
    #pragma unroll
    for (int ks = 0; ks < 4; ++ks)
        #pragma unroll
        for (int pt = 0; pt < 4; ++pt) {
            short8 bfr = *(const short8*)&fb[(pB + pt*16 + lm)*128 + ((ks*32 + 8*lg) ^ swzl)];
            facc[0][pt] = __builtin_amdgcn_mfma_f32_16x16x32_bf16(af2[0][ks], bfr, facc[0][pt], 0,0,0);
            facc[1][pt] = __builtin_amdgcn_mfma_f32_16x16x32_bf16(af2[1][ks], bfr, facc[1][pt], 0,0,0);
        }
    __syncthreads();   // all g reads done before f overwrites

    // ---- feats store (fp32) + f^T (bf16) in place
    {
        float b2r[2][4];
        #pragma unroll
        for (int ot = 0; ot < 2; ++ot)
            #pragma unroll
            for (int r = 0; r < 4; ++r) b2r[ot][r] = b2v[o0 + ot*16 + 4*lg + r];
        #pragma unroll
        for (int ot = 0; ot < 2; ++ot)
            #pragma unroll
            for (int pt = 0; pt < 4; ++pt) {
                f32x4 f = facc[ot][pt];
                float f0 = f[0] + b2r[ot][0], f1 = f[1] + b2r[ot][1];
                float f2 = f[2] + b2r[ot][2], f3 = f[3] + b2r[ot][3];
                int p = pt*16 + lm;              // window-local 0..63
                int py = p >> 3, px = p & 7;
                float* ob = out + (size_t)n*CH*HW + (size_t)(o0 + ot*16 + 4*lg)*HW
                                + (size_t)(h0 + py)*IMGW + w0c + win*8 + px;
                ob[0] = f0; ob[HW] = f1; ob[2*HW] = f2; ob[3*HW] = f3;
                uint2 pk; pk.x = pack2(f0, f1); pk.y = pack2(f2, f3);
                *(uint2*)&fb[(pB + p)*128 + ((o0 + ot*16 + 4*lg) ^ swzl)] = pk;
            }
    }
    __syncthreads();

    // ---- Gram (per window) + row LSE + loss partial
    const float invT = 1.f / temp[0];
    f32x4 sacc[4];
    #pragma unroll
    for (int qt = 0; qt < 4; ++qt) sacc[qt] = (f32x4){0.f,0.f,0.f,0.f};
    #pragma unroll
    for (int ks = 0; ks < 4; ++ks) {
        short8 afr = *(const short8*)&fb[(pB + 16*ow + lm)*128 + ((ks*32 + 8*lg) ^ swzl)];
        #pragma unroll
        for (int qt = 0; qt < 4; ++qt) {
            short8 bfr = *(const short8*)&fb[(pB + qt*16 + lm)*128 + ((ks*32 + 8*lg) ^ swzl)];
            sacc[qt] = __builtin_amdgcn_mfma_f32_16x16x32_bf16(afr, bfr, sacc[qt], 0,0,0);
        }
    }
    float lossAcc = 0.f;
    #pragma unroll
    for (int r = 0; r < 4; ++r) {
        float v0 = sacc[0][r]*invT, v1 = sacc[1][r]*invT;
        float v2 = sacc[2][r]*invT, v3 = sacc[3][r]*invT;
        float m = fmaxf(fmaxf(v0, v1), fmaxf(v2, v3));
        m = fmaxf(m, __shfl_xor(m, 1)); m = fmaxf(m, __shfl_xor(m, 2));
        m = fmaxf(m, __shfl_xor(m, 4)); m = fmaxf(m, __shfl_xor(m, 8));
        float s = __expf(v0-m) + __expf(v1-m) + __expf(v2-m) + __expf(v3-m);
        s += __shfl_xor(s, 1); s += __shfl_xor(s, 2);
        s += __shfl_xor(s, 4); s += __shfl_xor(s, 8);
        float lse = m + logf(s);
        if (lm == 4*lg + r) {
            float dv = (ow == 0) ? v0 : (ow == 1) ? v1 : (ow == 2) ? v2 : v3;
            lossAcc += lse - dv;
        }
    }
    lossAcc += __shfl_xor(lossAcc, 1);  lossAcc += __shfl_xor(lossAcc, 2);
    lossAcc += __shfl_xor(lossAcc, 4);  lossAcc += __shfl_xor(lossAcc, 8);
    lossAcc += __shfl_xor(lossAcc, 16); lossAcc += __shfl_xor(lossAcc, 32);
    if (l == 0) ws[WS_LOSS + (size_t)b*8 + wid] = lossAcc;
}

// ------------------------------------------ K4: deterministic loss reduction
__global__ void k4_loss(const float* __restrict__ ws, float* __restrict__ out) {
    __shared__ float red[4];
    int t = threadIdx.x;
    float s = 0.f;
    for (int i = t; i < 40960; i += 256) s += ws[WS_LOSS + i];
    #pragma unroll
    for (int off = 32; off > 0; off >>= 1) s += __shfl_down(s, off, 64);
    if ((t & 63) == 0) red[t >> 6] = s;
    __syncthreads();
    if (t == 0) out[FEATS_ELEMS] = (red[0] + red[1] + red[2] + red[3]) * (1.f/655360.f);
}

// ---------------------------------------------------------------- launcher
extern "C" void kernel_launch(void* const* d_in, const int* in_sizes, int n_in,
                              void* d_out, int out_size, void* d_ws, size_t ws_size,
                              hipStream_t stream) {
    (void)in_sizes; (void)n_in; (void)out_size; (void)ws_size;
    const float* x    = (const float*)d_in[0];
    const float* W1   = (const float*)d_in[1];
    const float* b1   = (const float*)d_in[2];
    const float* gnw  = (const float*)d_in[3];
    const float* gnb  = (const float*)d_in[4];
    const float* W2   = (const float*)d_in[5];
    const float* b2   = (const float*)d_in[6];
    const float* temp = (const float*)d_in[7];
    float* out = (float*)d_out;
    float* ws  = (float*)d_ws;

    hipLaunchKernelGGL(k0_init,    dim3(64),   dim3(256), 0, stream, W1, W2, ws);
    hipLaunchKernelGGL(k1_cache,   dim3(5120), dim3(512), 0, stream, x, ws, b1);
    hipLaunchKernelGGL(k2_final,   dim3(10),   dim3(256), 0, stream, gnw, gnb, ws);
    hipLaunchKernelGGL(k3_consume, dim3(5120), dim3(512), 0, stream, ws, b2, temp, out);
    hipLaunchKernelGGL(k4_loss,    dim3(1),    dim3(256), 0, stream, ws, out);
}

// Round 7
// 371.622 us; speedup vs baseline: 4.0096x; 1.0638x over previous
//
#include <hip/hip_runtime.h>
#include <hip/hip_bf16.h>
#include <math.h>

#define CH 128
#define IMGW 256
#define NIMG 10
#define HW 65536
#define FEATS_ELEMS ((size_t)NIMG*CH*HW)

typedef __attribute__((ext_vector_type(8))) short short8;
typedef __attribute__((ext_vector_type(4))) float f32x4;

// workspace layout (float offsets)
#define WS_W1BF 0          // W1 bf16 [128 o][128 c]
#define WS_W2BF 8192
#define WS_PART 16384      // [5120 swz-strips][16] block stat partials
#define WS_A    98304      // [10][128] rsig*gn_w
#define WS_CC   99584      // [10][128] affine constant
#define WS_LOSS 100864     // [5120*8] per-(strip,wave) loss partials
#define WS_HT   141824     // h cache: 5120 strips * 8192 floats (16384 bf16)

static __device__ __forceinline__ ushort f2bf(float f) {
    __hip_bfloat16 h = __float2bfloat16(f);
    return *reinterpret_cast<ushort*>(&h);
}
static __device__ __forceinline__ uint pack2(float a, float b) {
    return (uint)f2bf(a) | ((uint)f2bf(b) << 16);
}
static __device__ __forceinline__ float gelu_fast(float v) {
    float v2 = v*v;
    float z2 = v * fmaf(0.07135481627f, v2, 1.59576912161f);
    return v / (1.0f + __expf(-z2));
}
// 4x4 cross-lane transpose among lanes {l, l^16, l^32, l^48}
static __device__ __forceinline__ void xpose4(int lg, float& r0, float& r1,
                                              float& r2, float& r3) {
    float s0v = (lg&2) ? r0 : r2, s1v = (lg&2) ? r1 : r3;
    float u0 = __shfl_xor(s0v, 32), u1 = __shfl_xor(s1v, 32);
    if (lg&2) { r0 = u0; r1 = u1; } else { r2 = u0; r3 = u1; }
    float sA = (lg&1) ? r0 : r1; float uA = __shfl_xor(sA, 16);
    if (lg&1) r0 = uA; else r1 = uA;
    float sB = (lg&1) ? r2 : r3; float uB = __shfl_xor(sB, 16);
    if (lg&1) r2 = uB; else r3 = uB;
}

// ------------------------------------------------ K0: W->bf16
__global__ void k0_init(const float* __restrict__ W1, const float* __restrict__ W2,
                        float* __restrict__ ws) {
    int idx = blockIdx.x*256 + threadIdx.x;     // 0..16383
    uint* w1b = (uint*)(ws + WS_W1BF);
    uint* w2b = (uint*)(ws + WS_W2BF);
    if (idx < 8192) {
        w1b[idx] = pack2(W1[2*idx], W1[2*idx+1]);
    } else {
        int j = idx - 8192;
        w2b[j] = pack2(W2[2*j], W2[2*j+1]);
    }
}

// K1: stage x strip -> conv1(+b1) -> stats partials -> store h^T (bf16, swizzled)
// launch_bounds(512,4): 128 VGPR so the 8 NT loads + W1 fragments + acc all
// stay live; 2 blocks/CU. NT x-loads keep L2/L3 clean for the h cache.
__global__ __launch_bounds__(512, 4) void k1_cache(const float* __restrict__ x,
        float* ws, const float* __restrict__ b1v) {
    __shared__ __align__(16) ushort xT[128*128];   // x^T then h^T  (32 KB)
    __shared__ float sp[32];
    const int t = threadIdx.x, b = blockIdx.x;
    const int swz = (b & 7)*640 + (b >> 3);        // bijective, 5120%8==0
    const int n = swz >> 9, strip = swz & 511;
    const int h0 = (strip >> 4)*8, w0c = (strip & 15)*16;
    const int l = t & 63, wid = t >> 6;
    const int lm = l & 15, lg = l >> 4;
    const int swzl = 8*(lm&7);
    const ushort* w1b = (const ushort*)(ws + WS_W1BF);
    const int win = wid >> 2, ow = wid & 3;
    const int o0 = 32*ow, pB = win*64;

    // ---- issue all 8 x loads (NT), then weight-fragment loads, then transpose
    f32x4 v[8];
    {
        const float* xb = x + (size_t)n*CH*HW + (size_t)h0*IMGW + w0c;
        const int q = lm & 3, dy = (lm >> 2) + 4*(wid >> 2);
        #pragma unroll
        for (int i = 0; i < 8; ++i) {
            int gc = (wid & 3)*8 + i;
            int c = 4*gc + lg;
            v[i] = __builtin_nontemporal_load(
                       (const f32x4*)(xb + (size_t)c*HW + dy*IMGW + 4*q));
        }
    }
    short8 af[2][4];
    #pragma unroll
    for (int ot = 0; ot < 2; ++ot)
        #pragma unroll
        for (int ks = 0; ks < 4; ++ks)
            af[ot][ks] = *(const short8*)(w1b + (size_t)(o0 + ot*16 + lm)*128 + ks*32 + 8*lg);
    float bv[2][4];
    #pragma unroll
    for (int ot = 0; ot < 2; ++ot)
        #pragma unroll
        for (int r = 0; r < 4; ++r) bv[ot][r] = b1v[o0 + ot*16 + 4*lg + r];

    {
        const int q = lm & 3, dy = (lm >> 2) + 4*(wid >> 2);
        #pragma unroll
        for (int i = 0; i < 8; ++i) {
            int gc = (wid & 3)*8 + i;
            float r0 = v[i][0], r1 = v[i][1], r2 = v[i][2], r3 = v[i][3];
            xpose4(lg, r0, r1, r2, r3);
            int col = 4*q + lg;
            int p = (col >> 3)*64 + dy*8 + (col & 7);
            uint2 pk; pk.x = pack2(r0, r1); pk.y = pack2(r2, r3);
            *(uint2*)&xT[p*128 + ((4*gc) ^ (8*(p&7)))] = pk;
        }
    }
    __syncthreads();

    // ---- conv1 (h includes b1)
    f32x4 hacc[2][4];
    #pragma unroll
    for (int ot = 0; ot < 2; ++ot)
        #pragma unroll
        for (int pt = 0; pt < 4; ++pt)
            hacc[ot][pt] = (f32x4){bv[ot][0], bv[ot][1], bv[ot][2], bv[ot][3]};
    #pragma unroll
    for (int ks = 0; ks < 4; ++ks)
        #pragma unroll
        for (int pt = 0; pt < 4; ++pt) {
            short8 bfr = *(const short8*)&xT[(pB + pt*16 + lm)*128 + ((ks*32 + 8*lg) ^ swzl)];
            hacc[0][pt] = __builtin_amdgcn_mfma_f32_16x16x32_bf16(af[0][ks], bfr, hacc[0][pt], 0,0,0);
            hacc[1][pt] = __builtin_amdgcn_mfma_f32_16x16x32_bf16(af[1][ks], bfr, hacc[1][pt], 0,0,0);
        }

    // ---- stats: per-wave group sums -> sp
    float s1[2] = {0.f, 0.f}, s2[2] = {0.f, 0.f};
    #pragma unroll
    for (int ot = 0; ot < 2; ++ot)
        #pragma unroll
        for (int pt = 0; pt < 4; ++pt)
            #pragma unroll
            for (int r = 0; r < 4; ++r) {
                float h = hacc[ot][pt][r];
                s1[ot] += h; s2[ot] += h*h;
            }
    #pragma unroll
    for (int ot = 0; ot < 2; ++ot) {
        float a = s1[ot], q = s2[ot];
        #pragma unroll
        for (int off = 1; off < 64; off <<= 1) {
            a += __shfl_xor(a, off); q += __shfl_xor(q, off);
        }
        if (l == 0) { sp[wid*4 + ot*2] = a; sp[wid*4 + ot*2 + 1] = q; }
    }
    __syncthreads();   // sp ready; also: all conv1 xT reads complete

    if (t < 16) {
        int g = t & 7, which = t >> 3;
        int w0 = g >> 1, slot = (g & 1)*2 + which;
        float vv = sp[w0*4 + slot] + sp[(4 + w0)*4 + slot];
        ws[WS_PART + (size_t)swz*16 + which*8 + g] = vv;   // grouped by n
    }

    // ---- h^T write in-place into xT: [p][o^swz]
    #pragma unroll
    for (int ot = 0; ot < 2; ++ot)
        #pragma unroll
        for (int pt = 0; pt < 4; ++pt) {
            f32x4 h = hacc[ot][pt];
            int p = pB + pt*16 + lm;
            uint2 pk; pk.x = pack2(h[0], h[1]); pk.y = pack2(h[2], h[3]);
            *(uint2*)&xT[p*128 + ((o0 + ot*16 + 4*lg) ^ swzl)] = pk;
        }
    __syncthreads();

    // ---- stream LDS -> global h cache (plain stores: want L2/L3 residency)
    const uint4* srcv = (const uint4*)xT;
    uint4* dstv = (uint4*)(ws + WS_HT + (size_t)swz*8192);
    #pragma unroll
    for (int i = 0; i < 4; ++i) dstv[t + i*512] = srcv[t + i*512];
}

// K2: parallel reduce of block partials (grid 10 = one block per image)
__global__ __launch_bounds__(256) void k2_final(const float* __restrict__ gnw,
        const float* __restrict__ gnb, float* ws) {
    __shared__ float red[256];
    __shared__ float tot[16];
    __shared__ float muS[8], rsS[8];
    const int t = threadIdx.x, n = blockIdx.x;
    const int s = t & 15, i0 = t >> 4;
    const float* base = ws + WS_PART + (size_t)n*512*16;
    float p = 0.f;
    for (int k = 0; k < 32; ++k) p += base[(i0 + 16*k)*16 + s];
    red[t] = p;
    __syncthreads();
    if (t < 16) {
        float v = 0.f;
        #pragma unroll
        for (int j = 0; j < 16; ++j) v += red[j*16 + t];
        tot[t] = v;
    }
    __syncthreads();
    if (t < 8) {
        const float inv = 1.0f/1048576.0f;      // 16 ch * 65536 px
        float mu  = tot[t]*inv;
        float var = tot[8 + t]*inv - mu*mu;
        muS[t] = mu; rsS[t] = rsqrtf(var + 1e-5f);
    }
    __syncthreads();
    if (t < 128) {
        int g = t >> 4;
        float a = rsS[g]*gnw[t];
        ws[WS_A  + n*128 + t] = a;
        ws[WS_CC + n*128 + t] = gnb[t] - muS[g]*a;   // b1 already inside h
    }
}

// K3: 2-window strip (512 thr, 32 KB LDS), XCD-chunked swizzle matching k1.
// h strip loaded via global_load_lds (verbatim linear copy). 128 VGPR budget.
__global__ __launch_bounds__(512, 4) void k3_consume(float* ws,
        const float* __restrict__ b2v, const float* __restrict__ temp,
        float* __restrict__ out) {
    __shared__ __align__(16) ushort fb[128*128];   // h -> g -> f  (32 KB)
    const int t = threadIdx.x, b = blockIdx.x;
    const int swz = (b & 7)*640 + (b >> 3);        // same bijection as k1
    const int n = swz >> 9, strip = swz & 511;
    const int h0 = (strip >> 4)*8, w0c = (strip & 15)*16;
    const int l = t & 63, wid = t >> 6;
    const int lm = l & 15, lg = l >> 4;
    const int swzl = 8*(lm&7);
    const ushort* w2b = (const ushort*)(ws + WS_W2BF);

    // ---- load h strip: direct global->LDS (verbatim; lane-linear both sides)
    {
        const char* src = (const char*)(ws + WS_HT + (size_t)swz*8192);
        #pragma unroll
        for (int i = 0; i < 4; ++i) {
            __builtin_amdgcn_global_load_lds(
                (const __attribute__((address_space(1))) void*)(src + ((size_t)(t + i*512))*16),
                (__attribute__((address_space(3))) void*)&fb[(size_t)(t + i*512)*8],
                16, 0, 0);
        }
    }
    __syncthreads();

    // ---- GN affine + GELU, in place (4096 uint2 / 512 thr)
    {
        uint2* hu = (uint2*)fb;
        const float* aP = ws + WS_A  + n*128;
        const float* cP = ws + WS_CC + n*128;
        #pragma unroll
        for (int i = 0; i < 8; ++i) {
            int c0 = t + i*512;
            int p = c0 >> 5;
            int o = ((c0 & 31)*4) ^ (8*(p&7));
            uint2 v = hu[c0];
            float hv0 = __uint_as_float((v.x & 0xffffu) << 16);
            float hv1 = __uint_as_float(v.x & 0xffff0000u);
            float hv2 = __uint_as_float((v.y & 0xffffu) << 16);
            float hv3 = __uint_as_float(v.y & 0xffff0000u);
            float g0 = gelu_fast(fmaf(hv0, aP[o],   cP[o]));
            float g1 = gelu_fast(fmaf(hv1, aP[o+1], cP[o+1]));
            float g2 = gelu_fast(fmaf(hv2, aP[o+2], cP[o+2]));
            float g3 = gelu_fast(fmaf(hv3, aP[o+3], cP[o+3]));
            uint2 pk; pk.x = pack2(g0, g1); pk.y = pack2(g2, g3);
            hu[c0] = pk;
        }
    }
    __syncthreads();

    const int win = wid >> 2, ow = wid & 3;
    const int o0 = 32*ow, pB = win*64;

    // ---- conv2
    short8 af2[2][4];
    #pragma unroll
    for (int ot = 0; ot < 2; ++ot)
        #pragma unroll
        for (int ks = 0; ks < 4; ++ks)
            af2[ot][ks] = *(const short8*)(w2b + (size_t)(o0 + ot*16 + lm)*128 + ks*32 + 8*lg);
    f32x4 facc[2][4];
    #pragma unroll
    for (int ot = 0; ot < 2; ++ot)
        #pragma unroll
        for (int pt = 0; pt < 4; ++pt) facc[ot][pt] = (f32x4){0.f,0.f,0.f,0.f};
    #pragma unroll
    for (int ks = 0; ks < 4; ++ks)
        #pragma unroll
        for (int pt = 0; pt < 4; ++pt) {
            short8 bfr = *(const short8*)&fb[(pB + pt*16 + lm)*128 + ((ks*32 + 8*lg) ^ swzl)];
            facc[0][pt] = __builtin_amdgcn_mfma_f32_16x16x32_bf16(af2[0][ks], bfr, facc[0][pt], 0,0,0);
            facc[1][pt] = __builtin_amdgcn_mfma_f32_16x16x32_bf16(af2[1][ks], bfr, facc[1][pt], 0,0,0);
        }
    __syncthreads();   // all g reads done before f overwrites

    // ---- feats store (fp32) + f^T (bf16) in place
    {
        float b2r[2][4];
        #pragma unroll
        for (int ot = 0; ot < 2; ++ot)
            #pragma unroll
            for (int r = 0; r < 4; ++r) b2r[ot][r] = b2v[o0 + ot*16 + 4*lg + r];
        #pragma unroll
        for (int ot = 0; ot < 2; ++ot)
            #pragma unroll
            for (int pt = 0; pt < 4; ++pt) {
                f32x4 f = facc[ot][pt];
                float f0 = f[0] + b2r[ot][0], f1 = f[1] + b2r[ot][1];
                float f2 = f[2] + b2r[ot][2], f3 = f[3] + b2r[ot][3];
                int p = pt*16 + lm;              // window-local 0..63
                int py = p >> 3, px = p & 7;
                float* ob = out + (size_t)n*CH*HW + (size_t)(o0 + ot*16 + 4*lg)*HW
                                + (size_t)(h0 + py)*IMGW + w0c + win*8 + px;
                ob[0] = f0; ob[HW] = f1; ob[2*HW] = f2; ob[3*HW] = f3;
                uint2 pk; pk.x = pack2(f0, f1); pk.y = pack2(f2, f3);
                *(uint2*)&fb[(pB + p)*128 + ((o0 + ot*16 + 4*lg) ^ swzl)] = pk;
            }
    }
    __syncthreads();

    // ---- Gram (per window) + row LSE + loss partial
    const float invT = 1.f / temp[0];
    f32x4 sacc[4];
    #pragma unroll
    for (int qt = 0; qt < 4; ++qt) sacc[qt] = (f32x4){0.f,0.f,0.f,0.f};
    #pragma unroll
    for (int ks = 0; ks < 4; ++ks) {
        short8 afr = *(const short8*)&fb[(pB + 16*ow + lm)*128 + ((ks*32 + 8*lg) ^ swzl)];
        #pragma unroll
        for (int qt = 0; qt < 4; ++qt) {
            short8 bfr = *(const short8*)&fb[(pB + qt*16 + lm)*128 + ((ks*32 + 8*lg) ^ swzl)];
            sacc[qt] = __builtin_amdgcn_mfma_f32_16x16x32_bf16(afr, bfr, sacc[qt], 0,0,0);
        }
    }
    float lossAcc = 0.f;
    #pragma unroll
    for (int r = 0; r < 4; ++r) {
        float v0 = sacc[0][r]*invT, v1 = sacc[1][r]*invT;
        float v2 = sacc[2][r]*invT, v3 = sacc[3][r]*invT;
        float m = fmaxf(fmaxf(v0, v1), fmaxf(v2, v3));
        m = fmaxf(m, __shfl_xor(m, 1)); m = fmaxf(m, __shfl_xor(m, 2));
        m = fmaxf(m, __shfl_xor(m, 4)); m = fmaxf(m, __shfl_xor(m, 8));
        float s = __expf(v0-m) + __expf(v1-m) + __expf(v2-m) + __expf(v3-m);
        s += __shfl_xor(s, 1); s += __shfl_xor(s, 2);
        s += __shfl_xor(s, 4); s += __shfl_xor(s, 8);
        float lse = m + logf(s);
        if (lm == 4*lg + r) {
            float dv = (ow == 0) ? v0 : (ow == 1) ? v1 : (ow == 2) ? v2 : v3;
            lossAcc += lse - dv;
        }
    }
    lossAcc += __shfl_xor(lossAcc, 1);  lossAcc += __shfl_xor(lossAcc, 2);
    lossAcc += __shfl_xor(lossAcc, 4);  lossAcc += __shfl_xor(lossAcc, 8);
    lossAcc += __shfl_xor(lossAcc, 16); lossAcc += __shfl_xor(lossAcc, 32);
    if (l == 0) ws[WS_LOSS + (size_t)b*8 + wid] = lossAcc;
}

// ------------------------------------------ K4: deterministic loss reduction
__global__ void k4_loss(const float* __restrict__ ws, float* __restrict__ out) {
    __shared__ float red[4];
    int t = threadIdx.x;
    float s = 0.f;
    for (int i = t; i < 40960; i += 256) s += ws[WS_LOSS + i];
    #pragma unroll
    for (int off = 32; off > 0; off >>= 1) s += __shfl_down(s, off, 64);
    if ((t & 63) == 0) red[t >> 6] = s;
    __syncthreads();
    if (t == 0) out[FEATS_ELEMS] = (red[0] + red[1] + red[2] + red[3]) * (1.f/655360.f);
}

// ---------------------------------------------------------------- launcher
extern "C" void kernel_launch(void* const* d_in, const int* in_sizes, int n_in,
                              void* d_out, int out_size, void* d_ws, size_t ws_size,
                              hipStream_t stream) {
    (void)in_sizes; (void)n_in; (void)out_size; (void)ws_size;
    const float* x    = (const float*)d_in[0];
    const float* W1   = (const float*)d_in[1];
    const float* b1   = (const float*)d_in[2];
    const float* gnw  = (const float*)d_in[3];
    const float* gnb  = (const float*)d_in[4];
    const float* W2   = (const float*)d_in[5];
    const float* b2   = (const float*)d_in[6];
    const float* temp = (const float*)d_in[7];
    float* out = (float*)d_out;
    float* ws  = (float*)d_ws;

    hipLaunchKernelGGL(k0_init,    dim3(64),   dim3(256), 0, stream, W1, W2, ws);
    hipLaunchKernelGGL(k1_cache,   dim3(5120), dim3(512), 0, stream, x, ws, b1);
    hipLaunchKernelGGL(k2_final,   dim3(10),   dim3(256), 0, stream, gnw, gnb, ws);
    hipLaunchKernelGGL(k3_consume, dim3(5120), dim3(512), 0, stream, ws, b2, temp, out);
    hipLaunchKernelGGL(k4_loss,    dim3(1),    dim3(256), 0, stream, ws, out);
}

// Round 8
// 296.801 us; speedup vs baseline: 5.0204x; 1.2521x over previous
//
#include <hip/hip_runtime.h>
#include <hip/hip_bf16.h>
#include <math.h>

#define CH 128
#define IMGW 256
#define NIMG 10
#define HW 65536
#define FEATS_ELEMS ((size_t)NIMG*CH*HW)

typedef __attribute__((ext_vector_type(8))) short short8;
typedef __attribute__((ext_vector_type(4))) float f32x4;

// workspace layout (float offsets)
#define WS_W1BF 0          // W1 bf16 [128 o][128 c]
#define WS_W2BF 8192
#define WS_PART 16384      // [5120 swz-strips][16] block stat partials
#define WS_A    98304      // [10][128] rsig*gn_w
#define WS_CC   99584      // [10][128] affine constant
#define WS_LOSS 100864     // [5120*8] per-(strip,wave) loss partials
#define WS_HT   141824     // h cache: 5120 strips * 8192 floats (16384 bf16)

static __device__ __forceinline__ ushort f2bf(float f) {
    __hip_bfloat16 h = __float2bfloat16(f);
    return *reinterpret_cast<ushort*>(&h);
}
static __device__ __forceinline__ uint pack2(float a, float b) {
    return (uint)f2bf(a) | ((uint)f2bf(b) << 16);
}
static __device__ __forceinline__ float gelu_fast(float v) {
    float v2 = v*v;
    float z2 = v * fmaf(0.07135481627f, v2, 1.59576912161f);
    return v / (1.0f + __expf(-z2));
}
// 4x4 cross-lane transpose among lanes {l, l^16, l^32, l^48}
static __device__ __forceinline__ void xpose4(int lg, float& r0, float& r1,
                                              float& r2, float& r3) {
    float s0v = (lg&2) ? r0 : r2, s1v = (lg&2) ? r1 : r3;
    float u0 = __shfl_xor(s0v, 32), u1 = __shfl_xor(s1v, 32);
    if (lg&2) { r0 = u0; r1 = u1; } else { r2 = u0; r3 = u1; }
    float sA = (lg&1) ? r0 : r1; float uA = __shfl_xor(sA, 16);
    if (lg&1) r0 = uA; else r1 = uA;
    float sB = (lg&1) ? r2 : r3; float uB = __shfl_xor(sB, 16);
    if (lg&1) r2 = uB; else r3 = uB;
}

// ------------------------------------------------ K0: W->bf16
__global__ void k0_init(const float* __restrict__ W1, const float* __restrict__ W2,
                        float* __restrict__ ws) {
    int idx = blockIdx.x*256 + threadIdx.x;     // 0..16383
    uint* w1b = (uint*)(ws + WS_W1BF);
    uint* w2b = (uint*)(ws + WS_W2BF);
    if (idx < 8192) {
        w1b[idx] = pack2(W1[2*idx], W1[2*idx+1]);
    } else {
        int j = idx - 8192;
        w2b[j] = pack2(W2[2*j], W2[2*j+1]);
    }
}

// K1: stage x strip -> conv1(+b1) -> stats partials -> store h^T (bf16, swizzled)
// launch_bounds(512,4): 128 VGPR; NT x-loads keep L2/L3 clean for the h cache.
__global__ __launch_bounds__(512, 4) void k1_cache(const float* __restrict__ x,
        float* ws, const float* __restrict__ b1v) {
    __shared__ __align__(16) ushort xT[128*128];   // x^T then h^T  (32 KB)
    __shared__ float sp[32];
    const int t = threadIdx.x, b = blockIdx.x;
    const int swz = (b & 7)*640 + (b >> 3);        // bijective, 5120%8==0
    const int n = swz >> 9, strip = swz & 511;
    const int h0 = (strip >> 4)*8, w0c = (strip & 15)*16;
    const int l = t & 63, wid = t >> 6;
    const int lm = l & 15, lg = l >> 4;
    const int swzl = 8*(lm&7);
    const ushort* w1b = (const ushort*)(ws + WS_W1BF);
    const int win = wid >> 2, ow = wid & 3;
    const int o0 = 32*ow, pB = win*64;

    // ---- issue all 8 x loads (NT), then weight-fragment loads, then transpose
    f32x4 v[8];
    {
        const float* xb = x + (size_t)n*CH*HW + (size_t)h0*IMGW + w0c;
        const int q = lm & 3, dy = (lm >> 2) + 4*(wid >> 2);
        #pragma unroll
        for (int i = 0; i < 8; ++i) {
            int gc = (wid & 3)*8 + i;
            int c = 4*gc + lg;
            v[i] = __builtin_nontemporal_load(
                       (const f32x4*)(xb + (size_t)c*HW + dy*IMGW + 4*q));
        }
    }
    short8 af[2][4];
    #pragma unroll
    for (int ot = 0; ot < 2; ++ot)
        #pragma unroll
        for (int ks = 0; ks < 4; ++ks)
            af[ot][ks] = *(const short8*)(w1b + (size_t)(o0 + ot*16 + lm)*128 + ks*32 + 8*lg);
    float bv[2][4];
    #pragma unroll
    for (int ot = 0; ot < 2; ++ot)
        #pragma unroll
        for (int r = 0; r < 4; ++r) bv[ot][r] = b1v[o0 + ot*16 + 4*lg + r];

    {
        const int q = lm & 3, dy = (lm >> 2) + 4*(wid >> 2);
        #pragma unroll
        for (int i = 0; i < 8; ++i) {
            int gc = (wid & 3)*8 + i;
            float r0 = v[i][0], r1 = v[i][1], r2 = v[i][2], r3 = v[i][3];
            xpose4(lg, r0, r1, r2, r3);
            int col = 4*q + lg;
            int p = (col >> 3)*64 + dy*8 + (col & 7);
            uint2 pk; pk.x = pack2(r0, r1); pk.y = pack2(r2, r3);
            *(uint2*)&xT[p*128 + ((4*gc) ^ (8*(p&7)))] = pk;
        }
    }
    __syncthreads();

    // ---- conv1 (h includes b1)
    f32x4 hacc[2][4];
    #pragma unroll
    for (int ot = 0; ot < 2; ++ot)
        #pragma unroll
        for (int pt = 0; pt < 4; ++pt)
            hacc[ot][pt] = (f32x4){bv[ot][0], bv[ot][1], bv[ot][2], bv[ot][3]};
    #pragma unroll
    for (int ks = 0; ks < 4; ++ks)
        #pragma unroll
        for (int pt = 0; pt < 4; ++pt) {
            short8 bfr = *(const short8*)&xT[(pB + pt*16 + lm)*128 + ((ks*32 + 8*lg) ^ swzl)];
            hacc[0][pt] = __builtin_amdgcn_mfma_f32_16x16x32_bf16(af[0][ks], bfr, hacc[0][pt], 0,0,0);
            hacc[1][pt] = __builtin_amdgcn_mfma_f32_16x16x32_bf16(af[1][ks], bfr, hacc[1][pt], 0,0,0);
        }

    // ---- stats: per-wave group sums -> sp
    float s1[2] = {0.f, 0.f}, s2[2] = {0.f, 0.f};
    #pragma unroll
    for (int ot = 0; ot < 2; ++ot)
        #pragma unroll
        for (int pt = 0; pt < 4; ++pt)
            #pragma unroll
            for (int r = 0; r < 4; ++r) {
                float h = hacc[ot][pt][r];
                s1[ot] += h; s2[ot] += h*h;
            }
    #pragma unroll
    for (int ot = 0; ot < 2; ++ot) {
        float a = s1[ot], q = s2[ot];
        #pragma unroll
        for (int off = 1; off < 64; off <<= 1) {
            a += __shfl_xor(a, off); q += __shfl_xor(q, off);
        }
        if (l == 0) { sp[wid*4 + ot*2] = a; sp[wid*4 + ot*2 + 1] = q; }
    }
    __syncthreads();   // sp ready; also: all conv1 xT reads complete

    if (t < 16) {
        int g = t & 7, which = t >> 3;
        int w0 = g >> 1, slot = (g & 1)*2 + which;
        float vv = sp[w0*4 + slot] + sp[(4 + w0)*4 + slot];
        ws[WS_PART + (size_t)swz*16 + which*8 + g] = vv;   // grouped by n
    }

    // ---- h^T write in-place into xT: [p][o^swz]
    #pragma unroll
    for (int ot = 0; ot < 2; ++ot)
        #pragma unroll
        for (int pt = 0; pt < 4; ++pt) {
            f32x4 h = hacc[ot][pt];
            int p = pB + pt*16 + lm;
            uint2 pk; pk.x = pack2(h[0], h[1]); pk.y = pack2(h[2], h[3]);
            *(uint2*)&xT[p*128 + ((o0 + ot*16 + 4*lg) ^ swzl)] = pk;
        }
    __syncthreads();

    // ---- stream LDS -> global h cache (plain stores: want L2/L3 residency)
    const uint4* srcv = (const uint4*)xT;
    uint4* dstv = (uint4*)(ws + WS_HT + (size_t)swz*8192);
    #pragma unroll
    for (int i = 0; i < 4; ++i) dstv[t + i*512] = srcv[t + i*512];
}

// K2: parallel reduce of block partials (grid 10 = one block per image)
__global__ __launch_bounds__(256) void k2_final(const float* __restrict__ gnw,
        const float* __restrict__ gnb, float* ws) {
    __shared__ float red[256];
    __shared__ float tot[16];
    __shared__ float muS[8], rsS[8];
    const int t = threadIdx.x, n = blockIdx.x;
    const int s = t & 15, i0 = t >> 4;
    const float* base = ws + WS_PART + (size_t)n*512*16;
    float p = 0.f;
    for (int k = 0; k < 32; ++k) p += base[(i0 + 16*k)*16 + s];
    red[t] = p;
    __syncthreads();
    if (t < 16) {
        float v = 0.f;
        #pragma unroll
        for (int j = 0; j < 16; ++j) v += red[j*16 + t];
        tot[t] = v;
    }
    __syncthreads();
    if (t < 8) {
        const float inv = 1.0f/1048576.0f;      // 16 ch * 65536 px
        float mu  = tot[t]*inv;
        float var = tot[8 + t]*inv - mu*mu;
        muS[t] = mu; rsS[t] = rsqrtf(var + 1e-5f);
    }
    __syncthreads();
    if (t < 128) {
        int g = t >> 4;
        float a = rsS[g]*gnw[t];
        ws[WS_A  + n*128 + t] = a;
        ws[WS_CC + n*128 + t] = gnb[t] - muS[g]*a;   // b1 already inside h
    }
}

// K3: 2-window strip (512 thr). h via global_load_lds; GN+GELU in place;
// conv2; feats staged fp32 in LDS and streamed out as 64B float4 segments
// (NT stores); Gram + LSE from bf16 f^T.
__global__ __launch_bounds__(512, 4) void k3_consume(float* ws,
        const float* __restrict__ b2v, const float* __restrict__ temp,
        float* __restrict__ out) {
    __shared__ __align__(16) ushort fb[128*128];   // h -> g -> f^T bf16 (32 KB)
    __shared__ __align__(16) float  st[64*136];    // fp32 out staging  (34 KB)
    const int t = threadIdx.x, b = blockIdx.x;
    const int swz = (b & 7)*640 + (b >> 3);        // same bijection as k1
    const int n = swz >> 9, strip = swz & 511;
    const int h0 = (strip >> 4)*8, w0c = (strip & 15)*16;
    const int l = t & 63, wid = t >> 6;
    const int lm = l & 15, lg = l >> 4;
    const int swzl = 8*(lm&7);
    const ushort* w2b = (const ushort*)(ws + WS_W2BF);

    // ---- load h strip: direct global->LDS (verbatim; lane-linear both sides)
    {
        const char* src = (const char*)(ws + WS_HT + (size_t)swz*8192);
        #pragma unroll
        for (int i = 0; i < 4; ++i) {
            __builtin_amdgcn_global_load_lds(
                (const __attribute__((address_space(1))) void*)(src + ((size_t)(t + i*512))*16),
                (__attribute__((address_space(3))) void*)&fb[(size_t)(t + i*512)*8],
                16, 0, 0);
        }
    }
    __syncthreads();

    // ---- GN affine + GELU, in place (4096 uint2 / 512 thr)
    {
        uint2* hu = (uint2*)fb;
        const float* aP = ws + WS_A  + n*128;
        const float* cP = ws + WS_CC + n*128;
        #pragma unroll
        for (int i = 0; i < 8; ++i) {
            int c0 = t + i*512;
            int p = c0 >> 5;
            int o = ((c0 & 31)*4) ^ (8*(p&7));
            uint2 v = hu[c0];
            float hv0 = __uint_as_float((v.x & 0xffffu) << 16);
            float hv1 = __uint_as_float(v.x & 0xffff0000u);
            float hv2 = __uint_as_float((v.y & 0xffffu) << 16);
            float hv3 = __uint_as_float(v.y & 0xffff0000u);
            float g0 = gelu_fast(fmaf(hv0, aP[o],   cP[o]));
            float g1 = gelu_fast(fmaf(hv1, aP[o+1], cP[o+1]));
            float g2 = gelu_fast(fmaf(hv2, aP[o+2], cP[o+2]));
            float g3 = gelu_fast(fmaf(hv3, aP[o+3], cP[o+3]));
            uint2 pk; pk.x = pack2(g0, g1); pk.y = pack2(g2, g3);
            hu[c0] = pk;
        }
    }
    __syncthreads();

    const int win = wid >> 2, ow = wid & 3;
    const int o0 = 32*ow, pB = win*64;
    const int half = ow >> 1;                      // channel-half of this wave

    // ---- conv2
    short8 af2[2][4];
    #pragma unroll
    for (int ot = 0; ot < 2; ++ot)
        #pragma unroll
        for (int ks = 0; ks < 4; ++ks)
            af2[ot][ks] = *(const short8*)(w2b + (size_t)(o0 + ot*16 + lm)*128 + ks*32 + 8*lg);
    f32x4 facc[2][4];
    #pragma unroll
    for (int ot = 0; ot < 2; ++ot)
        #pragma unroll
        for (int pt = 0; pt < 4; ++pt) facc[ot][pt] = (f32x4){0.f,0.f,0.f,0.f};
    #pragma unroll
    for (int ks = 0; ks < 4; ++ks)
        #pragma unroll
        for (int pt = 0; pt < 4; ++pt) {
            short8 bfr = *(const short8*)&fb[(pB + pt*16 + lm)*128 + ((ks*32 + 8*lg) ^ swzl)];
            facc[0][pt] = __builtin_amdgcn_mfma_f32_16x16x32_bf16(af2[0][ks], bfr, facc[0][pt], 0,0,0);
            facc[1][pt] = __builtin_amdgcn_mfma_f32_16x16x32_bf16(af2[1][ks], bfr, facc[1][pt], 0,0,0);
        }
    // fold b2 into facc (single source of truth for both staging & Gram)
    #pragma unroll
    for (int ot = 0; ot < 2; ++ot) {
        float b2r0 = b2v[o0 + ot*16 + 4*lg + 0], b2r1 = b2v[o0 + ot*16 + 4*lg + 1];
        float b2r2 = b2v[o0 + ot*16 + 4*lg + 2], b2r3 = b2v[o0 + ot*16 + 4*lg + 3];
        #pragma unroll
        for (int pt = 0; pt < 4; ++pt) {
            facc[ot][pt][0] += b2r0; facc[ot][pt][1] += b2r1;
            facc[ot][pt][2] += b2r2; facc[ot][pt][3] += b2r3;
        }
    }
    __syncthreads();   // all g reads done before f^T overwrites fb

    // ---- f^T (bf16) into fb for Gram; half-0 waves also stage fp32
    #pragma unroll
    for (int ot = 0; ot < 2; ++ot)
        #pragma unroll
        for (int pt = 0; pt < 4; ++pt) {
            f32x4 f = facc[ot][pt];
            int p = pt*16 + lm;                    // window-local 0..63
            uint2 pk; pk.x = pack2(f[0], f[1]); pk.y = pack2(f[2], f[3]);
            *(uint2*)&fb[(pB + p)*128 + ((o0 + ot*16 + 4*lg) ^ swzl)] = pk;
        }
    if (half == 0) {
        #pragma unroll
        for (int ot = 0; ot < 2; ++ot)
            #pragma unroll
            for (int pt = 0; pt < 4; ++pt) {
                int p = pt*16 + lm, py = p >> 3, px = p & 7;
                int col = py*16 + win*8 + px;
                int cb = (ow & 1)*32 + ot*16 + 4*lg;
                f32x4 f = facc[ot][pt];
                st[(cb+0)*136 + col] = f[0];
                st[(cb+1)*136 + col] = f[1];
                st[(cb+2)*136 + col] = f[2];
                st[(cb+3)*136 + col] = f[3];
            }
    }
    __syncthreads();

    // ---- stream half 0 out (NT float4, 64B row segments), then Gram
    {
        #pragma unroll
        for (int i = 0; i < 4; ++i) {
            int f4 = t + i*512;
            int cl = f4 >> 5, rem = f4 & 31;
            int y = rem >> 2, xq = rem & 3;
            f32x4 val = *(const f32x4*)&st[cl*136 + y*16 + xq*4];
            __builtin_nontemporal_store(val,
                (f32x4*)(out + (size_t)n*CH*HW + (size_t)cl*HW
                             + (size_t)(h0 + y)*IMGW + w0c + xq*4));
        }
    }
    const float invT = 1.f / temp[0];
    f32x4 sacc[4];
    #pragma unroll
    for (int qt = 0; qt < 4; ++qt) sacc[qt] = (f32x4){0.f,0.f,0.f,0.f};
    #pragma unroll
    for (int ks = 0; ks < 4; ++ks) {
        short8 afr = *(const short8*)&fb[(pB + 16*ow + lm)*128 + ((ks*32 + 8*lg) ^ swzl)];
        #pragma unroll
        for (int qt = 0; qt < 4; ++qt) {
            short8 bfr = *(const short8*)&fb[(pB + qt*16 + lm)*128 + ((ks*32 + 8*lg) ^ swzl)];
            sacc[qt] = __builtin_amdgcn_mfma_f32_16x16x32_bf16(afr, bfr, sacc[qt], 0,0,0);
        }
    }
    __syncthreads();   // half-0 staging reads done

    // ---- stage + stream half 1
    if (half == 1) {
        #pragma unroll
        for (int ot = 0; ot < 2; ++ot)
            #pragma unroll
            for (int pt = 0; pt < 4; ++pt) {
                int p = pt*16 + lm, py = p >> 3, px = p & 7;
                int col = py*16 + win*8 + px;
                int cb = (ow & 1)*32 + ot*16 + 4*lg;
                f32x4 f = facc[ot][pt];
                st[(cb+0)*136 + col] = f[0];
                st[(cb+1)*136 + col] = f[1];
                st[(cb+2)*136 + col] = f[2];
                st[(cb+3)*136 + col] = f[3];
            }
    }
    __syncthreads();
    {
        #pragma unroll
        for (int i = 0; i < 4; ++i) {
            int f4 = t + i*512;
            int cl = f4 >> 5, rem = f4 & 31;
            int y = rem >> 2, xq = rem & 3;
            f32x4 val = *(const f32x4*)&st[cl*136 + y*16 + xq*4];
            __builtin_nontemporal_store(val,
                (f32x4*)(out + (size_t)n*CH*HW + (size_t)(64 + cl)*HW
                             + (size_t)(h0 + y)*IMGW + w0c + xq*4));
        }
    }

    // ---- row LSE + loss partial (registers only)
    float lossAcc = 0.f;
    #pragma unroll
    for (int r = 0; r < 4; ++r) {
        float v0 = sacc[0][r]*invT, v1 = sacc[1][r]*invT;
        float v2 = sacc[2][r]*invT, v3 = sacc[3][r]*invT;
        float m = fmaxf(fmaxf(v0, v1), fmaxf(v2, v3));
        m = fmaxf(m, __shfl_xor(m, 1)); m = fmaxf(m, __shfl_xor(m, 2));
        m = fmaxf(m, __shfl_xor(m, 4)); m = fmaxf(m, __shfl_xor(m, 8));
        float s = __expf(v0-m) + __expf(v1-m) + __expf(v2-m) + __expf(v3-m);
        s += __shfl_xor(s, 1); s += __shfl_xor(s, 2);
        s += __shfl_xor(s, 4); s += __shfl_xor(s, 8);
        float lse = m + logf(s);
        if (lm == 4*lg + r) {
            float dv = (ow == 0) ? v0 : (ow == 1) ? v1 : (ow == 2) ? v2 : v3;
            lossAcc += lse - dv;
        }
    }
    lossAcc += __shfl_xor(lossAcc, 1);  lossAcc += __shfl_xor(lossAcc, 2);
    lossAcc += __shfl_xor(lossAcc, 4);  lossAcc += __shfl_xor(lossAcc, 8);
    lossAcc += __shfl_xor(lossAcc, 16); lossAcc += __shfl_xor(lossAcc, 32);
    if (l == 0) ws[WS_LOSS + (size_t)b*8 + wid] = lossAcc;
}

// ------------------------------------------ K4: deterministic loss reduction
__global__ void k4_loss(const float* __restrict__ ws, float* __restrict__ out) {
    __shared__ float red[4];
    int t = threadIdx.x;
    float s = 0.f;
    for (int i = t; i < 40960; i += 256) s += ws[WS_LOSS + i];
    #pragma unroll
    for (int off = 32; off > 0; off >>= 1) s += __shfl_down(s, off, 64);
    if ((t & 63) == 0) red[t >> 6] = s;
    __syncthreads();
    if (t == 0) out[FEATS_ELEMS] = (red[0] + red[1] + red[2] + red[3]) * (1.f/655360.f);
}

// ---------------------------------------------------------------- launcher
extern "C" void kernel_launch(void* const* d_in, const int* in_sizes, int n_in,
                              void* d_out, int out_size, void* d_ws, size_t ws_size,
                              hipStream_t stream) {
    (void)in_sizes; (void)n_in; (void)out_size; (void)ws_size;
    const float* x    = (const float*)d_in[0];
    const float* W1   = (const float*)d_in[1];
    const float* b1   = (const float*)d_in[2];
    const float* gnw  = (const float*)d_in[3];
    const float* gnb  = (const float*)d_in[4];
    const float* W2   = (const float*)d_in[5];
    const float* b2   = (const float*)d_in[6];
    const float* temp = (const float*)d_in[7];
    float* out = (float*)d_out;
    float* ws  = (float*)d_ws;

    hipLaunchKernelGGL(k0_init,    dim3(64),   dim3(256), 0, stream, W1, W2, ws);
    hipLaunchKernelGGL(k1_cache,   dim3(5120), dim3(512), 0, stream, x, ws, b1);
    hipLaunchKernelGGL(k2_final,   dim3(10),   dim3(256), 0, stream, gnw, gnb, ws);
    hipLaunchKernelGGL(k3_consume, dim3(5120), dim3(512), 0, stream, ws, b2, temp, out);
    hipLaunchKernelGGL(k4_loss,    dim3(1),    dim3(256), 0, stream, ws, out);
}